// Round 1
// baseline (476.487 us; speedup 1.0000x reference)
//
#include <hip/hip_runtime.h>
#include <hip/hip_bf16.h>

// Non-local block, B=8 C=512 H=W=64, IC=256, N=HW/2=2048.
// Pipeline (per batch):
//   P = w_phi @ Y + b_phi      (256x4096, bf16)   viewed as Pv (512x2048)
//   T = w_theta @ X + b_theta  (256x4096, bf16)   viewed as Tv (512x2048)
//   G = w_g @ X + b_g          (256x4096, bf16)   viewed as Gv (512x2048)
//   S'[m,n] = sum_c Pv[c,m]*Tv[c,n]   (2048x2048)   == scores[n,m]
//   E[m,n]  = exp(S'[m,n]-max_n S'[m,:]) / sum_n exp(...)   (row softmax, in place)
//   OV[c,n] = sum_m Gv[c,m]*E[m,n]    (512x2048)   viewed as Or (256x4096)
//   out     = w_mask @ Or + b_mask + X  (512x4096 fp32)

typedef __attribute__((ext_vector_type(8))) short short8;
typedef __attribute__((ext_vector_type(4))) float f32x4;

#define BM 64
#define BN 64
#define BK 32
#define LDSS 40   // LDS row stride in bf16 elems: 80B rows -> 16B-aligned b128, 2-way-max bank aliasing

enum { EPI_BF16 = 0, EPI_BF16_BIAS = 1, EPI_F32_BIAS_RES = 2 };

__device__ __forceinline__ short f2bf(float f) {
  __hip_bfloat16 h = __float2bfloat16(f);
  union { __hip_bfloat16 h; short s; } u; u.h = h; return u.s;
}
__device__ __forceinline__ float bf2f(short s) {
  union { short s; __hip_bfloat16 h; } u; u.s = s; return __bfloat162float(u.h);
}

// Generic 64x64 tile MFMA GEMM: C[m,n] = sum_k A[m,k]*B[k,n] (+bias[m]) (+res)
// ATRANS: element A[m][k] lives at Ag[k*lda + m] (transposed storage).
template<typename TA, typename TB, bool ATRANS, int EPI>
__global__ __launch_bounds__(256)
void gemm_kernel(const TA* __restrict__ Ag, long sA, int lda,
                 const TB* __restrict__ Bg, long sB, int ldb,
                 void* __restrict__ Cg, long sC, int ldc,
                 int M, int N, int K,
                 const float* __restrict__ bias,
                 const float* __restrict__ res, long sRes)
{
  __shared__ short As[BM * LDSS];
  __shared__ short Bs[BN * LDSS];
  const int bz = blockIdx.z;
  const TA* A = Ag + (long)bz * sA;
  const TB* B = Bg + (long)bz * sB;
  const int m0 = blockIdx.y * BM;
  const int n0 = blockIdx.x * BN;
  const int t  = threadIdx.x;
  const int lane = t & 63;
  const int wave = t >> 6;

  f32x4 acc[4];
  #pragma unroll
  for (int i = 0; i < 4; i++)
    #pragma unroll
    for (int r = 0; r < 4; r++) acc[i][r] = 0.f;

  for (int kk = 0; kk < K; kk += BK) {
    // ---- stage A tile into As[m][k] ----
    if constexpr (!ATRANS) {
      const int row = t >> 2;          // 0..63
      const int kc  = (t & 3) * 8;     // 0,8,16,24
      const TA* src = A + (long)(m0 + row) * lda + (kk + kc);
      short8 apack;
      if constexpr (sizeof(TA) == 4) {
        const f32x4* s4 = (const f32x4*)src;
        f32x4 u0 = s4[0], u1 = s4[1];
        #pragma unroll
        for (int j = 0; j < 4; j++) { apack[j] = f2bf(u0[j]); apack[4 + j] = f2bf(u1[j]); }
      } else {
        apack = *(const short8*)src;
      }
      *(short8*)&As[row * LDSS + kc] = apack;
    } else {
      const int m  = t & 63;
      const int kc = (t >> 6) * 8;
      short8 apack;
      #pragma unroll
      for (int j = 0; j < 8; j++) {
        const TA* src = A + (long)(kk + kc + j) * lda + (m0 + m);
        if constexpr (sizeof(TA) == 4) apack[j] = f2bf(*(const float*)src);
        else                           apack[j] = *(const short*)src;
      }
      *(short8*)&As[m * LDSS + kc] = apack;
    }
    // ---- stage B tile into Bs[n][k] (transposed in LDS for contiguous frags) ----
    {
      const int n  = t & 63;
      const int kc = (t >> 6) * 8;
      short8 bpack;
      #pragma unroll
      for (int j = 0; j < 8; j++) {
        const TB* src = B + (long)(kk + kc + j) * ldb + (n0 + n);
        if constexpr (sizeof(TB) == 4) bpack[j] = f2bf(*(const float*)src);
        else                           bpack[j] = *(const short*)src;
      }
      *(short8*)&Bs[n * LDSS + kc] = bpack;
    }
    __syncthreads();

    // ---- MFMA: wave w computes rows [w*16, w*16+16) x all 64 cols ----
    const int fr = lane & 15;
    const int q8 = (lane >> 4) * 8;
    short8 afrag = *(const short8*)&As[(wave * 16 + fr) * LDSS + q8];
    #pragma unroll
    for (int ns = 0; ns < 4; ns++) {
      short8 bfrag = *(const short8*)&Bs[(ns * 16 + fr) * LDSS + q8];
      acc[ns] = __builtin_amdgcn_mfma_f32_16x16x32_bf16(afrag, bfrag, acc[ns], 0, 0, 0);
    }
    __syncthreads();
  }

  // ---- epilogue: D[row][col], col = lane&15, row = (lane>>4)*4 + reg ----
  const int colb = n0 + (lane & 15);
  const int rowb = m0 + wave * 16 + (lane >> 4) * 4;
  #pragma unroll
  for (int ns = 0; ns < 4; ns++) {
    const int c = colb + ns * 16;
    #pragma unroll
    for (int r = 0; r < 4; r++) {
      const int mr = rowb + r;
      float v = acc[ns][r];
      if constexpr (EPI == EPI_BF16) {
        ((short*)Cg)[(long)bz * sC + (long)mr * ldc + c] = f2bf(v);
      } else if constexpr (EPI == EPI_BF16_BIAS) {
        v += bias[mr];
        ((short*)Cg)[(long)bz * sC + (long)mr * ldc + c] = f2bf(v);
      } else {
        v += bias[mr] + res[(long)bz * sRes + (long)mr * ldc + c];
        ((float*)Cg)[(long)bz * sC + (long)mr * ldc + c] = v;
      }
    }
  }
}

// Row softmax over 2048-wide rows, in place, bf16. One block per row.
__global__ __launch_bounds__(256)
void softmax_kernel(short* __restrict__ SC)
{
  const long row = blockIdx.x;
  short* p = SC + row * 2048;
  const int t = threadIdx.x;
  const int lane = t & 63;
  const int wave = t >> 6;
  __shared__ float sred[4];

  short8 raw = *(short8*)&p[t * 8];
  float v[8];
  #pragma unroll
  for (int j = 0; j < 8; j++) v[j] = bf2f(raw[j]);

  float mx = v[0];
  #pragma unroll
  for (int j = 1; j < 8; j++) mx = fmaxf(mx, v[j]);
  #pragma unroll
  for (int off = 32; off > 0; off >>= 1) mx = fmaxf(mx, __shfl_down(mx, off));
  if (lane == 0) sred[wave] = mx;
  __syncthreads();
  const float M = fmaxf(fmaxf(sred[0], sred[1]), fmaxf(sred[2], sred[3]));
  __syncthreads();

  float e[8];
  float s = 0.f;
  #pragma unroll
  for (int j = 0; j < 8; j++) { e[j] = __expf(v[j] - M); s += e[j]; }
  #pragma unroll
  for (int off = 32; off > 0; off >>= 1) s += __shfl_down(s, off);
  if (lane == 0) sred[wave] = s;
  __syncthreads();
  const float Z = sred[0] + sred[1] + sred[2] + sred[3];
  const float rz = 1.f / Z;
  #pragma unroll
  for (int j = 0; j < 8; j++) raw[j] = f2bf(e[j] * rz);
  *(short8*)&p[t * 8] = raw;
}

extern "C" void kernel_launch(void* const* d_in, const int* in_sizes, int n_in,
                              void* d_out, int out_size, void* d_ws, size_t ws_size,
                              hipStream_t stream)
{
  (void)in_sizes; (void)n_in; (void)out_size; (void)ws_size;
  const float* x       = (const float*)d_in[0];
  const float* y       = (const float*)d_in[1];
  const float* w_phi   = (const float*)d_in[2];
  const float* b_phi   = (const float*)d_in[3];
  const float* w_theta = (const float*)d_in[4];
  const float* b_theta = (const float*)d_in[5];
  const float* w_g     = (const float*)d_in[6];
  const float* b_g     = (const float*)d_in[7];
  const float* w_mask  = (const float*)d_in[8];
  const float* b_mask  = (const float*)d_in[9];
  float* out = (float*)d_out;

  char* ws = (char*)d_ws;
  const long MB16 = 1L << 24;           // 16 MB
  short* P  = (short*)(ws);             // 8 x 256 x 4096 bf16 (== 8 x 512 x 2048)
  short* T  = (short*)(ws + MB16);
  short* G  = (short*)(ws + 2 * MB16);
  short* OV = (short*)(ws + 3 * MB16);  // 8 x 512 x 2048 bf16
  short* SC = (short*)(ws + 4 * MB16);  // 8 x 2048 x 2048 bf16 (scores -> attn in place)

  dim3 blk(256, 1, 1);

  // conv1x1 x3: M=256 N=4096 K=512, A = weight (fp32), B = image (fp32)
  dim3 gconv(4096 / BN, 256 / BM, 8);
  gemm_kernel<float, float, false, EPI_BF16_BIAS><<<gconv, blk, 0, stream>>>(
      w_phi, 0, 512, y, 512L * 4096, 4096, P, 256L * 4096, 4096,
      256, 4096, 512, b_phi, nullptr, 0);
  gemm_kernel<float, float, false, EPI_BF16_BIAS><<<gconv, blk, 0, stream>>>(
      w_theta, 0, 512, x, 512L * 4096, 4096, T, 256L * 4096, 4096,
      256, 4096, 512, b_theta, nullptr, 0);
  gemm_kernel<float, float, false, EPI_BF16_BIAS><<<gconv, blk, 0, stream>>>(
      w_g, 0, 512, x, 512L * 4096, 4096, G, 256L * 4096, 4096,
      256, 4096, 512, b_g, nullptr, 0);

  // scores: S'[m,n] = sum_c Pv[c,m] * Tv[c,n]; A = Pv transposed-access, lda=2048
  dim3 gsc(2048 / BN, 2048 / BM, 8);
  gemm_kernel<short, short, true, EPI_BF16><<<gsc, blk, 0, stream>>>(
      P, 512L * 2048, 2048, T, 512L * 2048, 2048, SC, 2048L * 2048, 2048,
      2048, 2048, 512, nullptr, nullptr, 0);

  // softmax over each row of S' (== softmax over scores axis n, per column m)
  softmax_kernel<<<8 * 2048, blk, 0, stream>>>(SC);

  // OV = Gv @ E : M=512 N=2048 K=2048
  dim3 gov(2048 / BN, 512 / BM, 8);
  gemm_kernel<short, short, false, EPI_BF16><<<gov, blk, 0, stream>>>(
      G, 512L * 2048, 2048, SC, 2048L * 2048, 2048, OV, 512L * 2048, 2048,
      512, 2048, 2048, nullptr, nullptr, 0);

  // out = w_mask @ Or + b_mask + x : M=512 N=4096 K=256
  dim3 gmask(4096 / BN, 512 / BM, 8);
  gemm_kernel<float, short, false, EPI_F32_BIAS_RES><<<gmask, blk, 0, stream>>>(
      w_mask, 0, 256, OV, 256L * 4096, 4096, out, 512L * 4096, 4096,
      512, 4096, 256, b_mask, x, 512L * 4096);
}

// Round 2
// 464.504 us; speedup vs baseline: 1.0258x; 1.0258x over previous
//
#include <hip/hip_runtime.h>
#include <hip/hip_bf16.h>

// Non-local block, B=8 C=512 H=W=64, IC=256, N2=HW=4096, N=2048 (channel-folded).
//
// Dataflow (all GEMMs are m97-style: C[i][j] = sum_k A[i][k]*BT[j][k], both
// operands k-contiguous bf16, 128x128 tile, global_load_lds(16B) staging):
//   prep:    w* -> bf16;  x,y -> xT,yT bf16 [b][4096][512]
//   convs:   P = Wphi·yT^T   (+bias)  [b][256][4096]   (same for T,G from xT)
//   transp:  Pv(512x2048 view) -> Pt [b][2048][512];  Tv -> Tt
//   scores:  ST[n][m] = sum_c Tt[n][c]*Pt[m][c]   ( = scores[b,n,m] )
//   softmax: column softmax over n (axis=1), in place on ST  -> attn[n][m]
//   OV:      OV[c][n] = sum_m Gv[c][m]*ST[n][m]   [b][512][2048]
//   transp:  Or(256x4096 view) -> OrT [b][4096][256]
//   mask:    out[o][n2] = sum_i Wm[o][i]*OrT[n2][i] + b_mask[o] + x[o][n2]  (fp32)

typedef __attribute__((ext_vector_type(8))) short short8;
typedef __attribute__((ext_vector_type(4))) short short4v;
typedef __attribute__((ext_vector_type(4))) float f32x4;

enum { EPI_BF16 = 0, EPI_BF16_BIAS = 1, EPI_F32_BIAS_RES = 2 };

__device__ __forceinline__ short f2bf(float f) {
  union { __hip_bfloat16 h; short s; } u; u.h = __float2bfloat16(f); return u.s;
}
__device__ __forceinline__ float bf2f(short s) {
  union { short s; __hip_bfloat16 h; } u; u.s = s; return __bfloat162float(u.h);
}

// async global->LDS copy, 16 B per lane. LDS dest must be wave-uniform base;
// HW lands lane i at base + i*16.
__device__ __forceinline__ void async_ld16(const void* g, void* l) {
  __builtin_amdgcn_global_load_lds(
      (const __attribute__((address_space(1))) unsigned int*)(unsigned long long)g,
      (__attribute__((address_space(3))) unsigned int*)(unsigned int)(unsigned long long)l,
      16, 0, 0);
}

// ---------------- m97-style GEMM: C[i][j] = sum_k A[i][k] * BT[j][k] --------
// A: [M][K] bf16 k-contig, BT: [N][K] bf16 k-contig. M,N multiples of 128,
// K multiple of 32. grid = (N/128, M/128, batch).
template<int EPI>
__global__ __launch_bounds__(256)
void gemm_bt(const short* __restrict__ Ag, long sA, int lda,
             const short* __restrict__ Bg, long sB, int ldb,
             void* __restrict__ Cg, long sC, int ldc,
             int K,
             const float* __restrict__ bias,
             const float* __restrict__ res, long sRes)
{
  __shared__ __align__(16) short As[128 * 32];
  __shared__ __align__(16) short Bs[128 * 32];
  const int bz = blockIdx.z;
  const short* A = Ag + (long)bz * sA;
  const short* B = Bg + (long)bz * sB;
  const int m0 = blockIdx.y * 128;
  const int n0 = blockIdx.x * 128;
  const int t = threadIdx.x;
  const int wv = t >> 6, ln = t & 63;
  const int wm = (wv >> 1) * 64, wn = (wv & 1) * 64;
  const int fr = ln & 15, q8 = (ln >> 4) * 8;

  f32x4 acc[4][4];
  #pragma unroll
  for (int i = 0; i < 4; i++)
    #pragma unroll
    for (int j = 0; j < 4; j++)
      #pragma unroll
      for (int r = 0; r < 4; r++) acc[i][j][r] = 0.f;

  const int rowA = t >> 2;            // 0..63 within half-tile
  const int kc = (t & 3) * 8;         // 0,8,16,24

  for (int kk = 0; kk < K; kk += 32) {
    // stage A tile [128][32] and B tile [128][32], 16B/lane async
    #pragma unroll
    for (int s = 0; s < 2; s++) {
      const short* ga = A + (long)(m0 + s * 64 + rowA) * lda + kk + kc;
      async_ld16(ga, As + (s * 256 + wv * 64) * 8);
      const short* gb = B + (long)(n0 + s * 64 + rowA) * ldb + kk + kc;
      async_ld16(gb, Bs + (s * 256 + wv * 64) * 8);
    }
    __syncthreads();   // drains vmcnt + barrier

    short8 af[4], bfr[4];
    #pragma unroll
    for (int mi = 0; mi < 4; mi++)
      af[mi] = *(const short8*)&As[(wm + mi * 16 + fr) * 32 + q8];
    #pragma unroll
    for (int ni = 0; ni < 4; ni++)
      bfr[ni] = *(const short8*)&Bs[(wn + ni * 16 + fr) * 32 + q8];
    #pragma unroll
    for (int mi = 0; mi < 4; mi++)
      #pragma unroll
      for (int ni = 0; ni < 4; ni++)
        acc[mi][ni] = __builtin_amdgcn_mfma_f32_16x16x32_bf16(af[mi], bfr[ni], acc[mi][ni], 0, 0, 0);
    __syncthreads();   // protect LDS before next-iter overwrite
  }

  // epilogue: frag (mi,ni): row = m0+wm+mi*16+(ln>>4)*4+r, col = n0+wn+ni*16+(ln&15)
  const int colb = n0 + wn + fr;
  const int rowb = m0 + wm + (ln >> 4) * 4;
  #pragma unroll
  for (int mi = 0; mi < 4; mi++) {
    #pragma unroll
    for (int r = 0; r < 4; r++) {
      const int mr = rowb + mi * 16 + r;
      float badd = 0.f;
      if constexpr (EPI != EPI_BF16) badd = bias[mr];
      #pragma unroll
      for (int ni = 0; ni < 4; ni++) {
        const int cc = colb + ni * 16;
        float v = acc[mi][ni][r] + badd;
        if constexpr (EPI == EPI_F32_BIAS_RES) {
          v += res[(long)bz * sRes + (long)mr * ldc + cc];
          ((float*)Cg)[(long)bz * sC + (long)mr * ldc + cc] = v;
        } else {
          ((short*)Cg)[(long)bz * sC + (long)mr * ldc + cc] = f2bf(v);
        }
      }
    }
  }
}

// ---------------- weight convert fp32->bf16, 4 x 131072 elems --------------
__global__ __launch_bounds__(256)
void wconv(const float* s0, const float* s1, const float* s2, const float* s3,
           short* d0, short* d1, short* d2, short* d3)
{
  const int seg = blockIdx.x >> 6;
  const int blk = blockIdx.x & 63;
  const float* s = seg == 0 ? s0 : seg == 1 ? s1 : seg == 2 ? s2 : s3;
  short* d = seg == 0 ? d0 : seg == 1 ? d1 : seg == 2 ? d2 : d3;
  const int i0 = blk * 2048 + threadIdx.x * 8;
  f32x4 a = *(const f32x4*)&s[i0];
  f32x4 b = *(const f32x4*)&s[i0 + 4];
  short8 o;
  #pragma unroll
  for (int j = 0; j < 4; j++) { o[j] = f2bf(a[j]); o[4 + j] = f2bf(b[j]); }
  *(short8*)&d[i0] = o;
}

// ---------------- convert + transpose: img[b][512][4096] f32 -> imgT[b][4096][512] bf16
__global__ __launch_bounds__(256)
void convtr(const float* __restrict__ x, const float* __restrict__ y,
            short* __restrict__ xT, short* __restrict__ yT)
{
  __shared__ short Ts[64 * 65];
  const int z = blockIdx.z;
  const float* src = (z < 8 ? x : y) + (long)(z & 7) * 512 * 4096;
  short* dst = (z < 8 ? xT : yT) + (long)(z & 7) * 4096 * 512;
  const int c0 = blockIdx.y * 64;   // over 512
  const int n0 = blockIdx.x * 64;   // over 4096
  const int t = threadIdx.x;
  #pragma unroll
  for (int i = 0; i < 4; i++) {
    const int idx4 = t + i * 256;
    const int rr = idx4 >> 4, p4 = idx4 & 15;
    f32x4 v = *(const f32x4*)&src[(long)(c0 + rr) * 4096 + n0 + p4 * 4];
    #pragma unroll
    for (int j = 0; j < 4; j++) Ts[(p4 * 4 + j) * 65 + rr] = f2bf(v[j]);
  }
  __syncthreads();
  #pragma unroll
  for (int i = 0; i < 4; i++) {
    const int idx4 = t + i * 256;
    const int cc = idx4 >> 4, p4 = idx4 & 15;
    short4v o;
    #pragma unroll
    for (int j = 0; j < 4; j++) o[j] = Ts[cc * 65 + p4 * 4 + j];
    *(short4v*)&dst[(long)(n0 + cc) * 512 + c0 + p4 * 4] = o;
  }
}

// ---------------- bf16 transpose: src[R][C] -> dst[C][R] per batch ----------
// z < 8: (s0,d0) batch z ; z >= 8: (s1,d1) batch z-8
__global__ __launch_bounds__(256)
void tr_bf16(const short* __restrict__ s0, short* __restrict__ d0,
             const short* __restrict__ s1, short* __restrict__ d1,
             int R, int C)
{
  __shared__ short Ts[64 * 65];
  const int z = blockIdx.z;
  const short* src = (z < 8 ? s0 : s1) + (long)(z & 7) * R * C;
  short* dst = (z < 8 ? d0 : d1) + (long)(z & 7) * R * C;
  const int r0 = blockIdx.y * 64;
  const int c0 = blockIdx.x * 64;
  const int t = threadIdx.x;
  #pragma unroll
  for (int i = 0; i < 4; i++) {
    const int idx4 = t + i * 256;
    const int rr = idx4 >> 4, p4 = idx4 & 15;
    short4v v = *(const short4v*)&src[(long)(r0 + rr) * C + c0 + p4 * 4];
    #pragma unroll
    for (int j = 0; j < 4; j++) Ts[(p4 * 4 + j) * 65 + rr] = v[j];
  }
  __syncthreads();
  #pragma unroll
  for (int i = 0; i < 4; i++) {
    const int idx4 = t + i * 256;
    const int cc = idx4 >> 4, p4 = idx4 & 15;
    short4v o;
    #pragma unroll
    for (int j = 0; j < 4; j++) o[j] = Ts[cc * 65 + p4 * 4 + j];
    *(short4v*)&dst[(long)(c0 + cc) * R + r0 + p4 * 4] = o;
  }
}

// ---------------- column softmax over ST[b][2048 rows n][2048 cols m] -------
// softmax over n (row index) per column m. 3 phases.
__global__ __launch_bounds__(256)
void smax_stats(const short* __restrict__ ST, float2* __restrict__ pstats)
{
  // grid (8 colchunk, 8 rowchunk, 8 batch); block: 32 colgroups x 8 rowgroups
  __shared__ float2 red[8 * 256];
  const int b = blockIdx.z, rb = blockIdx.y, cb = blockIdx.x;
  const short* base = ST + ((long)b << 22);
  const int t = threadIdx.x;
  const int cg = t & 31, rg = t >> 5;
  const int col0 = cb * 256 + cg * 8;
  float m[8], s[8];
  #pragma unroll
  for (int j = 0; j < 8; j++) { m[j] = -3.0e38f; s[j] = 0.f; }
  for (int ii = 0; ii < 32; ii++) {
    const int row = rb * 256 + rg * 32 + ii;
    short8 v8 = *(const short8*)&base[(long)row * 2048 + col0];
    #pragma unroll
    for (int j = 0; j < 8; j++) {
      float v = bf2f(v8[j]);
      if (v > m[j]) { s[j] = s[j] * __expf(m[j] - v) + 1.f; m[j] = v; }
      else          { s[j] += __expf(v - m[j]); }
    }
  }
  #pragma unroll
  for (int j = 0; j < 8; j++) { red[rg * 256 + cg * 8 + j] = make_float2(m[j], s[j]); }
  __syncthreads();
  if (rg == 0) {
    #pragma unroll
    for (int j = 0; j < 8; j++) {
      const int col = cg * 8 + j;
      float M = -3.0e38f;
      #pragma unroll
      for (int r = 0; r < 8; r++) M = fmaxf(M, red[r * 256 + col].x);
      float S = 0.f;
      #pragma unroll
      for (int r = 0; r < 8; r++) { float2 p = red[r * 256 + col]; S += p.y * __expf(p.x - M); }
      pstats[(((long)(b * 8 + rb)) << 11) + cb * 256 + col] = make_float2(M, S);
    }
  }
}

__global__ __launch_bounds__(256)
void smax_final(const float2* __restrict__ pstats, float2* __restrict__ fstats)
{
  const int g = blockIdx.x * 256 + threadIdx.x;   // 0..16383
  const int b = g >> 11, col = g & 2047;
  float M = -3.0e38f;
  float2 pv[8];
  #pragma unroll
  for (int rc = 0; rc < 8; rc++) {
    pv[rc] = pstats[(((long)(b * 8 + rc)) << 11) + col];
    M = fmaxf(M, pv[rc].x);
  }
  float S = 0.f;
  #pragma unroll
  for (int rc = 0; rc < 8; rc++) S += pv[rc].y * __expf(pv[rc].x - M);
  fstats[g] = make_float2(M, 1.f / S);
}

__global__ __launch_bounds__(256)
void smax_norm(short* __restrict__ ST, const float2* __restrict__ fstats)
{
  __shared__ float2 st[2048];
  const long row = blockIdx.x;          // 0..16383 (b*2048 + n)
  const int b = (int)(row >> 11);
  const float2* fs = fstats + ((long)b << 11);
  const int t = threadIdx.x;
  #pragma unroll
  for (int i = 0; i < 8; i++) st[i * 256 + t] = fs[i * 256 + t];
  __syncthreads();
  short* p = ST + row * 2048;
  short8 v8 = *(short8*)&p[t * 8];
  #pragma unroll
  for (int j = 0; j < 8; j++) {
    float2 f = st[t * 8 + j];
    v8[j] = f2bf(__expf(bf2f(v8[j]) - f.x) * f.y);
  }
  *(short8*)&p[t * 8] = v8;
}

// ---------------------------------------------------------------------------
extern "C" void kernel_launch(void* const* d_in, const int* in_sizes, int n_in,
                              void* d_out, int out_size, void* d_ws, size_t ws_size,
                              hipStream_t stream)
{
  (void)in_sizes; (void)n_in; (void)out_size; (void)ws_size;
  const float* x       = (const float*)d_in[0];
  const float* y       = (const float*)d_in[1];
  const float* w_phi   = (const float*)d_in[2];
  const float* b_phi   = (const float*)d_in[3];
  const float* w_theta = (const float*)d_in[4];
  const float* b_theta = (const float*)d_in[5];
  const float* w_g     = (const float*)d_in[6];
  const float* b_g     = (const float*)d_in[7];
  const float* w_mask  = (const float*)d_in[8];
  const float* b_mask  = (const float*)d_in[9];
  float* out = (float*)d_out;

  char* ws = (char*)d_ws;
  const long MB = 1L << 20;
  short* wphi_bf   = (short*)(ws + 0);
  short* wtheta_bf = (short*)(ws + 256 * 1024);
  short* wg_bf     = (short*)(ws + 512 * 1024);
  short* wmask_bf  = (short*)(ws + 768 * 1024);
  short* xT = (short*)(ws + 1 * MB);    // [8][4096][512] bf16, 32MB
  short* yT = (short*)(ws + 33 * MB);   // 32MB
  short* P  = (short*)(ws + 65 * MB);   // [8][256][4096] bf16, 16MB
  short* T  = (short*)(ws + 81 * MB);
  short* G  = (short*)(ws + 97 * MB);
  short* Pt = (short*)(ws + 1 * MB);    // [8][2048][512], reuse xT (dead)
  short* Tt = (short*)(ws + 17 * MB);
  short* ST = (short*)(ws + 33 * MB);   // [8][2048][2048] bf16, 64MB (over yT/P/T, dead)
  float2* pstats = (float2*)(ws + 113 * MB);  // [8][8][2048] float2, 1MB
  float2* fstats = (float2*)(ws + 114 * MB);  // [8][2048] float2, 128KB
  short* OV  = (short*)(ws + 1 * MB);   // [8][512][2048], reuse Pt (dead)
  short* OrT = (short*)(ws + 17 * MB);  // [8][4096][256], reuse Tt (dead)

  dim3 blk(256, 1, 1);

  // prep
  wconv<<<dim3(256, 1, 1), blk, 0, stream>>>(w_phi, w_theta, w_g, w_mask,
                                             wphi_bf, wtheta_bf, wg_bf, wmask_bf);
  convtr<<<dim3(64, 8, 16), blk, 0, stream>>>(x, y, xT, yT);

  // convs: M=256, N=4096, K=512
  dim3 gconv(4096 / 128, 256 / 128, 8);
  gemm_bt<EPI_BF16_BIAS><<<gconv, blk, 0, stream>>>(
      wphi_bf, 0, 512, yT, 4096L * 512, 512, P, 256L * 4096, 4096, 512, b_phi, nullptr, 0);
  gemm_bt<EPI_BF16_BIAS><<<gconv, blk, 0, stream>>>(
      wtheta_bf, 0, 512, xT, 4096L * 512, 512, T, 256L * 4096, 4096, 512, b_theta, nullptr, 0);
  gemm_bt<EPI_BF16_BIAS><<<gconv, blk, 0, stream>>>(
      wg_bf, 0, 512, xT, 4096L * 512, 512, G, 256L * 4096, 4096, 512, b_g, nullptr, 0);

  // transpose Pv,Tv (512x2048 views) -> Pt,Tt (2048x512)
  tr_bf16<<<dim3(2048 / 64, 512 / 64, 16), blk, 0, stream>>>(P, Pt, T, Tt, 512, 2048);

  // scores: ST[n][m], M=N=2048, K=512
  dim3 gsc(2048 / 128, 2048 / 128, 8);
  gemm_bt<EPI_BF16><<<gsc, blk, 0, stream>>>(
      Tt, 2048L * 512, 512, Pt, 2048L * 512, 512, ST, 2048L * 2048, 2048, 512,
      nullptr, nullptr, 0);

  // column softmax (over n) in place
  smax_stats<<<dim3(8, 8, 8), blk, 0, stream>>>(ST, pstats);
  smax_final<<<dim3(64, 1, 1), blk, 0, stream>>>(pstats, fstats);
  smax_norm<<<dim3(16384, 1, 1), blk, 0, stream>>>(ST, fstats);

  // OV[c][n] = sum_m Gv[c][m]*attn[n][m] : M=512, N=2048, K=2048
  dim3 gov(2048 / 128, 512 / 128, 8);
  gemm_bt<EPI_BF16><<<gov, blk, 0, stream>>>(
      G, 512L * 2048, 2048, ST, 2048L * 2048, 2048, OV, 512L * 2048, 2048, 2048,
      nullptr, nullptr, 0);

  // transpose Or (256x4096 view of OV) -> OrT (4096x256)
  tr_bf16<<<dim3(4096 / 64, 256 / 64, 8), blk, 0, stream>>>(OV, OrT, nullptr, nullptr, 256, 4096);

  // mask: out = Wm·OrT^T + b_mask + x : M=512, N=4096, K=256, fp32 out
  dim3 gmask(4096 / 128, 512 / 128, 8);
  gemm_bt<EPI_F32_BIAS_RES><<<gmask, blk, 0, stream>>>(
      wmask_bf, 0, 256, OrT, 4096L * 256, 256, out, 512L * 4096, 4096, 256,
      b_mask, x, 512L * 4096);
}

// Round 3
// 424.087 us; speedup vs baseline: 1.1236x; 1.0953x over previous
//
#include <hip/hip_runtime.h>
#include <hip/hip_bf16.h>

// Non-local block, B=8 C=512 H=W=64, IC=256, N2=HW=4096, N=2048 (folded).
//
// Round-3 dataflow (9 launches, no standalone transposes of P/T/OV):
//   wconv2:  weights -> bf16; w_mask -> two zero-interleaved [512][512] variants
//   convtr:  x,y f32 [b][512][4096] -> xT,yT bf16 [b][4096][512] (contiguous 64MB)
//   conv_pt: TPT2[r][o] = imgT[r]·W^T + b  (r<32768: theta/x, r>=32768: phi/y)
//   conv_g:  G = Wg·xT^T + b_g  [b][256][4096]  (== Gv [512][2048] k-contig)
//   scores:  ST[b][n][m] = sum_h sum_o TT2[h*2048+n][o]*PT2[h*2048+m][o]
//            + fused per-column (m) partial softmax stats -> pstats[b][16][2048]
//   final:   reduce 16 partials -> fstats[b][m] = (M, 1/Z)
//   norm:    ST <- exp(ST - M[m]) * (1/Z[m])  (attn, bf16, in place)
//   OV:      OVT[b][n][c] = sum_m attn[n][m]*Gv[c][m]   [2048][512]
//   mask:    out[o][n2] = sum_c Wm2h[o][c]*OVT[n2&2047][c] + b_mask[o] + x[o][n2]

typedef __attribute__((ext_vector_type(8))) short short8;
typedef __attribute__((ext_vector_type(4))) short short4v;
typedef __attribute__((ext_vector_type(4))) float f32x4;

enum { EPI_BF16 = 0, EPI_BF16_BIAS = 1 };

__device__ __forceinline__ short f2bf(float f) {
  union { __hip_bfloat16 h; short s; } u; u.h = __float2bfloat16(f); return u.s;
}
__device__ __forceinline__ float bf2f(short s) {
  union { short s; __hip_bfloat16 h; } u; u.s = s; return __bfloat162float(u.h);
}

__device__ __forceinline__ void async_ld16(const void* g, void* l) {
  __builtin_amdgcn_global_load_lds(
      (const __attribute__((address_space(1))) unsigned int*)(unsigned long long)g,
      (__attribute__((address_space(3))) unsigned int*)(unsigned int)(unsigned long long)l,
      16, 0, 0);
}

// ---------------- m97-style GEMM core: C[i][j] = sum_k A[i][k]*BT[j][k] ----
template<int EPI>
__global__ __launch_bounds__(256)
void gemm_bt(const short* __restrict__ Ag, long sA, int lda,
             const short* __restrict__ Bg, long sB, int ldb,
             short* __restrict__ Cg, long sC, int ldc,
             int K, const float* __restrict__ bias)
{
  __shared__ __align__(16) short As[128 * 32];
  __shared__ __align__(16) short Bs[128 * 32];
  const int bz = blockIdx.z;
  const short* A = Ag + (long)bz * sA;
  const short* B = Bg + (long)bz * sB;
  const int m0 = blockIdx.y * 128;
  const int n0 = blockIdx.x * 128;
  const int t = threadIdx.x;
  const int wv = t >> 6, ln = t & 63;
  const int wm = (wv >> 1) * 64, wn = (wv & 1) * 64;
  const int fr = ln & 15, q8 = (ln >> 4) * 8;
  const int rowA = t >> 2, kc = (t & 3) * 8;

  f32x4 acc[4][4];
  #pragma unroll
  for (int i = 0; i < 4; i++)
    #pragma unroll
    for (int j = 0; j < 4; j++)
      #pragma unroll
      for (int r = 0; r < 4; r++) acc[i][j][r] = 0.f;

  for (int kk = 0; kk < K; kk += 32) {
    #pragma unroll
    for (int s = 0; s < 2; s++) {
      async_ld16(A + (long)(m0 + s * 64 + rowA) * lda + kk + kc, As + (s * 256 + wv * 64) * 8);
      async_ld16(B + (long)(n0 + s * 64 + rowA) * ldb + kk + kc, Bs + (s * 256 + wv * 64) * 8);
    }
    __syncthreads();
    short8 af[4], bfr[4];
    #pragma unroll
    for (int mi = 0; mi < 4; mi++) af[mi] = *(const short8*)&As[(wm + mi * 16 + fr) * 32 + q8];
    #pragma unroll
    for (int ni = 0; ni < 4; ni++) bfr[ni] = *(const short8*)&Bs[(wn + ni * 16 + fr) * 32 + q8];
    #pragma unroll
    for (int mi = 0; mi < 4; mi++)
      #pragma unroll
      for (int ni = 0; ni < 4; ni++)
        acc[mi][ni] = __builtin_amdgcn_mfma_f32_16x16x32_bf16(af[mi], bfr[ni], acc[mi][ni], 0, 0, 0);
    __syncthreads();
  }

  const int colb = n0 + wn + fr;
  const int rowb = m0 + wm + (ln >> 4) * 4;
  #pragma unroll
  for (int mi = 0; mi < 4; mi++) {
    #pragma unroll
    for (int r = 0; r < 4; r++) {
      const int mr = rowb + mi * 16 + r;
      float badd = 0.f;
      if constexpr (EPI == EPI_BF16_BIAS) badd = bias[mr];
      #pragma unroll
      for (int ni = 0; ni < 4; ni++)
        Cg[(long)bz * sC + (long)mr * ldc + colb + ni * 16] = f2bf(acc[mi][ni][r] + badd);
    }
  }
}

// ---------------- pixel-major phi/theta conv: TPT2 = imgT · W^T + b --------
// imgT: [65536][512] (rows 0..32767 from xT/theta, 32768.. from yT/phi)
// grid (2, 512, 1). Column bias.
__global__ __launch_bounds__(256)
void conv_pt(const short* __restrict__ imgT,
             const short* __restrict__ wth, const short* __restrict__ wph,
             const float* __restrict__ bth, const float* __restrict__ bph,
             short* __restrict__ TPT2)
{
  __shared__ __align__(16) short As[128 * 32];
  __shared__ __align__(16) short Bs[128 * 32];
  const int m0 = blockIdx.y * 128;      // pixel rows (global, 0..65535)
  const int n0 = blockIdx.x * 128;      // o cols (0 or 128)
  const bool isphi = blockIdx.y >= 256;
  const short* A = imgT + (long)m0 * 512;
  const short* B = isphi ? wph : wth;
  const float* bias = isphi ? bph : bth;
  const int t = threadIdx.x;
  const int wv = t >> 6, ln = t & 63;
  const int wm = (wv >> 1) * 64, wn = (wv & 1) * 64;
  const int fr = ln & 15, q8 = (ln >> 4) * 8;
  const int rowA = t >> 2, kc = (t & 3) * 8;

  f32x4 acc[4][4];
  #pragma unroll
  for (int i = 0; i < 4; i++)
    #pragma unroll
    for (int j = 0; j < 4; j++)
      #pragma unroll
      for (int r = 0; r < 4; r++) acc[i][j][r] = 0.f;

  for (int kk = 0; kk < 512; kk += 32) {
    #pragma unroll
    for (int s = 0; s < 2; s++) {
      async_ld16(A + (long)(s * 64 + rowA) * 512 + kk + kc, As + (s * 256 + wv * 64) * 8);
      async_ld16(B + (long)(n0 + s * 64 + rowA) * 512 + kk + kc, Bs + (s * 256 + wv * 64) * 8);
    }
    __syncthreads();
    short8 af[4], bfr[4];
    #pragma unroll
    for (int mi = 0; mi < 4; mi++) af[mi] = *(const short8*)&As[(wm + mi * 16 + fr) * 32 + q8];
    #pragma unroll
    for (int ni = 0; ni < 4; ni++) bfr[ni] = *(const short8*)&Bs[(wn + ni * 16 + fr) * 32 + q8];
    #pragma unroll
    for (int mi = 0; mi < 4; mi++)
      #pragma unroll
      for (int ni = 0; ni < 4; ni++)
        acc[mi][ni] = __builtin_amdgcn_mfma_f32_16x16x32_bf16(af[mi], bfr[ni], acc[mi][ni], 0, 0, 0);
    __syncthreads();
  }

  const int colb = n0 + wn + fr;
  const int rowb = m0 + wm + (ln >> 4) * 4;
  float cb[4];
  #pragma unroll
  for (int ni = 0; ni < 4; ni++) cb[ni] = bias[colb + ni * 16];
  #pragma unroll
  for (int mi = 0; mi < 4; mi++)
    #pragma unroll
    for (int r = 0; r < 4; r++) {
      const long mr = rowb + mi * 16 + r;
      #pragma unroll
      for (int ni = 0; ni < 4; ni++)
        TPT2[mr * 256 + colb + ni * 16] = f2bf(acc[mi][ni][r] + cb[ni]);
    }
}

// ---------------- scores + fused partial softmax stats ---------------------
// grid (16 m-blocks, 16 n-blocks, 8 b). Two K=256 segments (h=0,1).
__global__ __launch_bounds__(256)
void scores_k(const short* __restrict__ TT2, const short* __restrict__ PT2,
              short* __restrict__ ST, float2* __restrict__ pstats)
{
  __shared__ __align__(16) short As[128 * 32];
  __shared__ __align__(16) short Bs[128 * 32];
  const int bz = blockIdx.z, by = blockIdx.y, bx = blockIdx.x;
  const int t = threadIdx.x;
  const int wv = t >> 6, ln = t & 63;
  const int wm = (wv >> 1) * 64, wn = (wv & 1) * 64;
  const int fr = ln & 15, q8 = (ln >> 4) * 8;
  const int rowA = t >> 2, kc = (t & 3) * 8;

  f32x4 acc[4][4];
  #pragma unroll
  for (int i = 0; i < 4; i++)
    #pragma unroll
    for (int j = 0; j < 4; j++)
      #pragma unroll
      for (int r = 0; r < 4; r++) acc[i][j][r] = 0.f;

  #pragma unroll
  for (int h = 0; h < 2; h++) {
    const short* Aseg = TT2 + ((long)(bz * 4096 + h * 2048 + by * 128)) * 256;
    const short* Bseg = PT2 + ((long)(bz * 4096 + h * 2048 + bx * 128)) * 256;
    for (int kk = 0; kk < 256; kk += 32) {
      #pragma unroll
      for (int s = 0; s < 2; s++) {
        async_ld16(Aseg + (long)(s * 64 + rowA) * 256 + kk + kc, As + (s * 256 + wv * 64) * 8);
        async_ld16(Bseg + (long)(s * 64 + rowA) * 256 + kk + kc, Bs + (s * 256 + wv * 64) * 8);
      }
      __syncthreads();
      short8 af[4], bfr[4];
      #pragma unroll
      for (int mi = 0; mi < 4; mi++) af[mi] = *(const short8*)&As[(wm + mi * 16 + fr) * 32 + q8];
      #pragma unroll
      for (int ni = 0; ni < 4; ni++) bfr[ni] = *(const short8*)&Bs[(wn + ni * 16 + fr) * 32 + q8];
      #pragma unroll
      for (int mi = 0; mi < 4; mi++)
        #pragma unroll
        for (int ni = 0; ni < 4; ni++)
          acc[mi][ni] = __builtin_amdgcn_mfma_f32_16x16x32_bf16(af[mi], bfr[ni], acc[mi][ni], 0, 0, 0);
      __syncthreads();
    }
  }

  // write raw scores bf16
  const int colb = bx * 128 + wn + fr;
  const int rowb = by * 128 + wm + (ln >> 4) * 4;
  short* base = ST + ((long)bz << 22);
  #pragma unroll
  for (int mi = 0; mi < 4; mi++)
    #pragma unroll
    for (int r = 0; r < 4; r++) {
      const long mr = rowb + mi * 16 + r;
      #pragma unroll
      for (int ni = 0; ni < 4; ni++)
        base[mr * 2048 + colb + ni * 16] = f2bf(acc[mi][ni][r]);
    }

  // per-column partial stats over this block's 128 rows
  float pm[4], ps[4];
  #pragma unroll
  for (int ni = 0; ni < 4; ni++) {
    float mx = acc[0][ni][0];
    #pragma unroll
    for (int mi = 0; mi < 4; mi++)
      #pragma unroll
      for (int r = 0; r < 4; r++) mx = fmaxf(mx, acc[mi][ni][r]);
    float s = 0.f;
    #pragma unroll
    for (int mi = 0; mi < 4; mi++)
      #pragma unroll
      for (int r = 0; r < 4; r++) s += __expf(acc[mi][ni][r] - mx);
    pm[ni] = mx; ps[ni] = s;
  }
  #pragma unroll
  for (int off = 16; off <= 32; off <<= 1) {
    #pragma unroll
    for (int ni = 0; ni < 4; ni++) {
      float om = __shfl_xor(pm[ni], off);
      float os = __shfl_xor(ps[ni], off);
      float M = fmaxf(pm[ni], om);
      ps[ni] = ps[ni] * __expf(pm[ni] - M) + os * __expf(om - M);
      pm[ni] = M;
    }
  }
  float2* part = (float2*)As;    // reuse LDS (safe: loop ended with barrier)
  if (ln < 16) {
    #pragma unroll
    for (int ni = 0; ni < 4; ni++)
      part[(wv >> 1) * 128 + wn + ni * 16 + fr] = make_float2(pm[ni], ps[ni]);
  }
  __syncthreads();
  if (t < 128) {
    float2 a = part[t], b = part[128 + t];
    float M = fmaxf(a.x, b.x);
    float S = a.y * __expf(a.x - M) + b.y * __expf(b.x - M);
    pstats[((long)(bz * 16 + by)) * 2048 + bx * 128 + t] = make_float2(M, S);
  }
}

// ---------------- reduce 16 partials -> (M, 1/Z) per column ----------------
__global__ __launch_bounds__(256)
void smax_final(const float2* __restrict__ pstats, float2* __restrict__ fstats)
{
  const int g = blockIdx.x * 256 + threadIdx.x;   // 0..16383
  const int b = g >> 11, col = g & 2047;
  float2 pv[16];
  float M = -3.0e38f;
  #pragma unroll
  for (int rc = 0; rc < 16; rc++) {
    pv[rc] = pstats[((long)(b * 16 + rc)) * 2048 + col];
    M = fmaxf(M, pv[rc].x);
  }
  float S = 0.f;
  #pragma unroll
  for (int rc = 0; rc < 16; rc++) S += pv[rc].y * __expf(pv[rc].x - M);
  fstats[g] = make_float2(M, 1.f / S);
}

// ---------------- normalize: ST <- exp(ST - M[m]) / Z[m] -------------------
__global__ __launch_bounds__(256)
void smax_norm(short* __restrict__ ST, const float2* __restrict__ fstats)
{
  __shared__ float2 st[2048];
  const long row = blockIdx.x;          // b*2048 + n
  const int b = (int)(row >> 11);
  const float2* fs = fstats + ((long)b << 11);
  const int t = threadIdx.x;
  #pragma unroll
  for (int i = 0; i < 8; i++) st[i * 256 + t] = fs[i * 256 + t];
  __syncthreads();
  short* p = ST + row * 2048;
  short8 v8 = *(short8*)&p[t * 8];
  #pragma unroll
  for (int j = 0; j < 8; j++) {
    float2 f = st[t * 8 + j];
    v8[j] = f2bf(__expf(bf2f(v8[j]) - f.x) * f.y);
  }
  *(short8*)&p[t * 8] = v8;
}

// ---------------- mask GEMM: zero-interleaved weights, fused bias+residual -
// grid (32 n2-blocks, 4 o-blocks, 8 b). K=512.
__global__ __launch_bounds__(256)
void mask_k(const short* __restrict__ Wm20, const short* __restrict__ Wm21,
            const short* __restrict__ OVT, const float* __restrict__ bmask,
            const float* __restrict__ x, float* __restrict__ out)
{
  __shared__ __align__(16) short As[128 * 32];
  __shared__ __align__(16) short Bs[128 * 32];
  const int bz = blockIdx.z;
  const int n0 = blockIdx.x * 128;        // n2 col base
  const int m0 = blockIdx.y * 128;        // o row base
  const short* A = (n0 >= 2048) ? Wm21 : Wm20;               // [512][512]
  const short* B = OVT + ((long)bz << 20) + (long)(n0 & 2047) * 512;
  const int t = threadIdx.x;
  const int wv = t >> 6, ln = t & 63;
  const int wm = (wv >> 1) * 64, wn = (wv & 1) * 64;
  const int fr = ln & 15, q8 = (ln >> 4) * 8;
  const int rowA = t >> 2, kc = (t & 3) * 8;

  f32x4 acc[4][4];
  #pragma unroll
  for (int i = 0; i < 4; i++)
    #pragma unroll
    for (int j = 0; j < 4; j++)
      #pragma unroll
      for (int r = 0; r < 4; r++) acc[i][j][r] = 0.f;

  for (int kk = 0; kk < 512; kk += 32) {
    #pragma unroll
    for (int s = 0; s < 2; s++) {
      async_ld16(A + (long)(m0 + s * 64 + rowA) * 512 + kk + kc, As + (s * 256 + wv * 64) * 8);
      async_ld16(B + (long)(s * 64 + rowA) * 512 + kk + kc, Bs + (s * 256 + wv * 64) * 8);
    }
    __syncthreads();
    short8 af[4], bfr[4];
    #pragma unroll
    for (int mi = 0; mi < 4; mi++) af[mi] = *(const short8*)&As[(wm + mi * 16 + fr) * 32 + q8];
    #pragma unroll
    for (int ni = 0; ni < 4; ni++) bfr[ni] = *(const short8*)&Bs[(wn + ni * 16 + fr) * 32 + q8];
    #pragma unroll
    for (int mi = 0; mi < 4; mi++)
      #pragma unroll
      for (int ni = 0; ni < 4; ni++)
        acc[mi][ni] = __builtin_amdgcn_mfma_f32_16x16x32_bf16(af[mi], bfr[ni], acc[mi][ni], 0, 0, 0);
    __syncthreads();
  }

  const int colb = n0 + wn + fr;
  const int rowb = m0 + wm + (ln >> 4) * 4;
  #pragma unroll
  for (int mi = 0; mi < 4; mi++)
    #pragma unroll
    for (int r = 0; r < 4; r++) {
      const int mr = rowb + mi * 16 + r;
      const float badd = bmask[mr];
      const long rbase = ((long)bz * 512 + mr) * 4096;
      #pragma unroll
      for (int ni = 0; ni < 4; ni++) {
        const int cc = colb + ni * 16;
        out[rbase + cc] = acc[mi][ni][r] + badd + x[rbase + cc];
      }
    }
}

// ---------------- weight prep ----------------------------------------------
__global__ __launch_bounds__(256)
void wconv2(const float* w_phi, const float* w_theta, const float* w_g,
            const float* w_mask,
            short* wph, short* wth, short* wg, short* Wm20, short* Wm21)
{
  const int seg = blockIdx.x >> 6;
  const int blk = blockIdx.x & 63;
  const int i0 = blk * 2048 + threadIdx.x * 8;
  if (seg < 3) {
    const float* s = seg == 0 ? w_phi : seg == 1 ? w_theta : w_g;
    short* d = seg == 0 ? wph : seg == 1 ? wth : wg;
    f32x4 a = *(const f32x4*)&s[i0];
    f32x4 b = *(const f32x4*)&s[i0 + 4];
    short8 o;
    #pragma unroll
    for (int j = 0; j < 4; j++) { o[j] = f2bf(a[j]); o[4 + j] = f2bf(b[j]); }
    *(short8*)&d[i0] = o;
  } else {
    // w_mask [512][256] -> Wm2h[o][2j+h] = Wm[o][j], else 0
    const int o = i0 >> 8, j0 = i0 & 255;
    f32x4 a = *(const f32x4*)&w_mask[i0];
    f32x4 b = *(const f32x4*)&w_mask[i0 + 4];
    short v[8];
    #pragma unroll
    for (int j = 0; j < 4; j++) { v[j] = f2bf(a[j]); v[4 + j] = f2bf(b[j]); }
    short8 a0, a1, b0, b1;
    #pragma unroll
    for (int j = 0; j < 4; j++) {
      a0[2 * j] = v[j];     a0[2 * j + 1] = 0;
      a1[2 * j] = v[4 + j]; a1[2 * j + 1] = 0;
      b0[2 * j] = 0;        b0[2 * j + 1] = v[j];
      b1[2 * j] = 0;        b1[2 * j + 1] = v[4 + j];
    }
    const long base = (long)o * 512 + 2 * j0;
    *(short8*)&Wm20[base] = a0; *(short8*)&Wm20[base + 8] = a1;
    *(short8*)&Wm21[base] = b0; *(short8*)&Wm21[base + 8] = b1;
  }
}

// ---------------- convert + transpose images -------------------------------
__global__ __launch_bounds__(256)
void convtr(const float* __restrict__ x, const float* __restrict__ y,
            short* __restrict__ xT, short* __restrict__ yT)
{
  __shared__ short Ts[64 * 65];
  const int z = blockIdx.z;
  const float* src = (z < 8 ? x : y) + (long)(z & 7) * 512 * 4096;
  short* dst = (z < 8 ? xT : yT) + (long)(z & 7) * 4096 * 512;
  const int c0 = blockIdx.y * 64;
  const int n0 = blockIdx.x * 64;
  const int t = threadIdx.x;
  #pragma unroll
  for (int i = 0; i < 4; i++) {
    const int idx4 = t + i * 256;
    const int rr = idx4 >> 4, p4 = idx4 & 15;
    f32x4 v = *(const f32x4*)&src[(long)(c0 + rr) * 4096 + n0 + p4 * 4];
    #pragma unroll
    for (int j = 0; j < 4; j++) Ts[(p4 * 4 + j) * 65 + rr] = f2bf(v[j]);
  }
  __syncthreads();
  #pragma unroll
  for (int i = 0; i < 4; i++) {
    const int idx4 = t + i * 256;
    const int cc = idx4 >> 4, p4 = idx4 & 15;
    short4v o;
    #pragma unroll
    for (int j = 0; j < 4; j++) o[j] = Ts[cc * 65 + p4 * 4 + j];
    *(short4v*)&dst[(long)(n0 + cc) * 512 + c0 + p4 * 4] = o;
  }
}

// ---------------------------------------------------------------------------
extern "C" void kernel_launch(void* const* d_in, const int* in_sizes, int n_in,
                              void* d_out, int out_size, void* d_ws, size_t ws_size,
                              hipStream_t stream)
{
  (void)in_sizes; (void)n_in; (void)out_size; (void)ws_size;
  const float* x       = (const float*)d_in[0];
  const float* y       = (const float*)d_in[1];
  const float* w_phi   = (const float*)d_in[2];
  const float* b_phi   = (const float*)d_in[3];
  const float* w_theta = (const float*)d_in[4];
  const float* b_theta = (const float*)d_in[5];
  const float* w_g     = (const float*)d_in[6];
  const float* b_g     = (const float*)d_in[7];
  const float* w_mask  = (const float*)d_in[8];
  const float* b_mask  = (const float*)d_in[9];
  float* out = (float*)d_out;

  char* ws = (char*)d_ws;
  const long MB = 1L << 20;
  short* wph  = (short*)(ws + 0);
  short* wth  = (short*)(ws + 256 * 1024);
  short* wg   = (short*)(ws + 512 * 1024);
  short* Wm20 = (short*)(ws + 768 * 1024);
  short* Wm21 = (short*)(ws + 1280 * 1024);
  short* xT   = (short*)(ws + 2 * MB);    // [8][4096][512], 32MB
  short* yT   = (short*)(ws + 34 * MB);   // 32MB (contiguous after xT)
  short* TPT2 = (short*)(ws + 66 * MB);   // [65536][256], 32MB
  short* G    = (short*)(ws + 98 * MB);   // [8][256][4096], 16MB
  short* ST   = (short*)(ws + 2 * MB);    // [8][2048][2048], 64MB (over xT/yT, dead)
  float2* pstats = (float2*)(ws + 114 * MB);  // [8][16][2048], 2MB
  float2* fstats = (float2*)(ws + 116 * MB);  // [8][2048], 128KB
  short* OVT  = (short*)(ws + 66 * MB);   // [8][2048][512], 16MB (over TPT2, dead)

  dim3 blk(256, 1, 1);

  wconv2<<<dim3(256, 1, 1), blk, 0, stream>>>(w_phi, w_theta, w_g, w_mask,
                                              wph, wth, wg, Wm20, Wm21);
  convtr<<<dim3(64, 8, 16), blk, 0, stream>>>(x, y, xT, yT);

  // phi+theta pixel-major conv: one launch, 1024 blocks
  conv_pt<<<dim3(2, 512, 1), blk, 0, stream>>>(xT, wth, wph, b_theta, b_phi, TPT2);

  // g conv channel-major: G[b][256][4096]
  gemm_bt<EPI_BF16_BIAS><<<dim3(32, 2, 8), blk, 0, stream>>>(
      wg, 0, 512, xT, 4096L * 512, 512, G, 1048576L, 4096, 512, b_g);

  // scores + fused partial stats
  scores_k<<<dim3(16, 16, 8), blk, 0, stream>>>(TPT2, TPT2 + 32768L * 256, ST, pstats);
  smax_final<<<dim3(64, 1, 1), blk, 0, stream>>>(pstats, fstats);
  smax_norm<<<dim3(16384, 1, 1), blk, 0, stream>>>(ST, fstats);

  // OVT[n][c] = sum_m attn[n][m] * Gv[c][m]
  gemm_bt<EPI_BF16><<<dim3(4, 16, 8), blk, 0, stream>>>(
      ST, 4194304L, 2048, G, 1048576L, 2048, OVT, 1048576L, 512, 2048, nullptr);

  // mask + bias + residual, fp32 out
  mask_k<<<dim3(32, 4, 8), blk, 0, stream>>>(Wm20, Wm21, OVT, b_mask, x, out);
}

// Round 4
// 404.786 us; speedup vs baseline: 1.1771x; 1.0477x over previous
//
#include <hip/hip_runtime.h>
#include <hip/hip_bf16.h>

// Non-local block, B=8 C=512 H=W=64, IC=256, N2=HW=4096, N=2048 (folded).
//
// Round-4 dataflow (9 launches):
//   wconv2:  weights -> bf16; w_mask -> two zero-interleaved [512][512]
//   convtr:  x,y f32 -> xT,yT bf16 [b][4096][512]
//   conv_pt: TPT2[r][o] = imgT[r]·W^T + b  (r<32768 theta/x, else phi/y)
//   conv_g8: G[b][256][4096] = Wg·xT^T + b_g        (8-wave GEMM)
//   scores:  E[b][n][m] = exp(sum_h sum_o TT2·PT2)  (UNNORMALIZED exp)
//            + fused per-column partial sums -> pstats[b][16][2048]
//   zfinal:  invZ[b][m] = 1 / sum_16 pstats
//   g_scale: G *= invZ[m]  (in place; folds softmax denom into G columns)
//   ov8:     OVT[b][n][c] = sum_m E[n][m]*G''[c][m]  (8-wave GEMM)
//   mask:    out = Wm2h·OVT^T + b_mask + x  (fp32)

typedef __attribute__((ext_vector_type(8))) short short8;
typedef __attribute__((ext_vector_type(4))) short short4v;
typedef __attribute__((ext_vector_type(4))) float f32x4;

enum { EPI_BF16 = 0, EPI_BF16_BIAS = 1 };

__device__ __forceinline__ short f2bf(float f) {
  union { __hip_bfloat16 h; short s; } u; u.h = __float2bfloat16(f); return u.s;
}
__device__ __forceinline__ float bf2f(short s) {
  union { short s; __hip_bfloat16 h; } u; u.s = s; return __bfloat162float(u.h);
}

__device__ __forceinline__ void async_ld16(const void* g, void* l) {
  __builtin_amdgcn_global_load_lds(
      (const __attribute__((address_space(1))) unsigned int*)(unsigned long long)g,
      (__attribute__((address_space(3))) unsigned int*)(unsigned int)(unsigned long long)l,
      16, 0, 0);
}

// ---------------- 8-wave 128x128 GEMM: C[i][j] = sum_k A[i][k]*BT[j][k] ----
// 512 threads; wave wv: rows [(wv>>1)*32,+32), cols [(wv&1)*64,+64).
// One 16B async load per thread per operand per BK=32 step.
template<int EPI>
__global__ __launch_bounds__(512, 4)
void gemm8(const short* __restrict__ Ag, long sA, int lda,
           const short* __restrict__ Bg, long sB, int ldb,
           short* __restrict__ Cg, long sC, int ldc,
           int K, const float* __restrict__ bias)
{
  __shared__ __align__(16) short As[128 * 32];
  __shared__ __align__(16) short Bs[128 * 32];
  const int bz = blockIdx.z;
  const short* A = Ag + (long)bz * sA;
  const short* B = Bg + (long)bz * sB;
  const int m0 = blockIdx.y * 128;
  const int n0 = blockIdx.x * 128;
  const int t = threadIdx.x;
  const int wv = t >> 6, ln = t & 63;
  const int wr = wv >> 1, wc = wv & 1;
  const int fr = ln & 15, q8 = (ln >> 4) * 8;
  const int rowA = t >> 2, kc = (t & 3) * 8;

  f32x4 acc[2][4];
  #pragma unroll
  for (int i = 0; i < 2; i++)
    #pragma unroll
    for (int j = 0; j < 4; j++)
      #pragma unroll
      for (int r = 0; r < 4; r++) acc[i][j][r] = 0.f;

  for (int kk = 0; kk < K; kk += 32) {
    async_ld16(A + (long)(m0 + rowA) * lda + kk + kc, As + wv * 512);
    async_ld16(B + (long)(n0 + rowA) * ldb + kk + kc, Bs + wv * 512);
    __syncthreads();
    short8 af[2], bfr[4];
    #pragma unroll
    for (int mi = 0; mi < 2; mi++) af[mi] = *(const short8*)&As[(wr * 32 + mi * 16 + fr) * 32 + q8];
    #pragma unroll
    for (int ni = 0; ni < 4; ni++) bfr[ni] = *(const short8*)&Bs[(wc * 64 + ni * 16 + fr) * 32 + q8];
    #pragma unroll
    for (int mi = 0; mi < 2; mi++)
      #pragma unroll
      for (int ni = 0; ni < 4; ni++)
        acc[mi][ni] = __builtin_amdgcn_mfma_f32_16x16x32_bf16(af[mi], bfr[ni], acc[mi][ni], 0, 0, 0);
    __syncthreads();
  }

  const int colb = n0 + wc * 64 + fr;
  const int rowb = m0 + wr * 32 + (ln >> 4) * 4;
  #pragma unroll
  for (int mi = 0; mi < 2; mi++)
    #pragma unroll
    for (int r = 0; r < 4; r++) {
      const int mr = rowb + mi * 16 + r;
      float badd = 0.f;
      if constexpr (EPI == EPI_BF16_BIAS) badd = bias[mr];
      #pragma unroll
      for (int ni = 0; ni < 4; ni++)
        Cg[(long)bz * sC + (long)mr * ldc + colb + ni * 16] = f2bf(acc[mi][ni][r] + badd);
    }
}

// ---------------- pixel-major phi/theta conv: TPT2 = imgT · W^T + b --------
__global__ __launch_bounds__(256)
void conv_pt(const short* __restrict__ imgT,
             const short* __restrict__ wth, const short* __restrict__ wph,
             const float* __restrict__ bth, const float* __restrict__ bph,
             short* __restrict__ TPT2)
{
  __shared__ __align__(16) short As[128 * 32];
  __shared__ __align__(16) short Bs[128 * 32];
  const int m0 = blockIdx.y * 128;
  const int n0 = blockIdx.x * 128;
  const bool isphi = blockIdx.y >= 256;
  const short* A = imgT + (long)m0 * 512;
  const short* B = isphi ? wph : wth;
  const float* bias = isphi ? bph : bth;
  const int t = threadIdx.x;
  const int wv = t >> 6, ln = t & 63;
  const int wm = (wv >> 1) * 64, wn = (wv & 1) * 64;
  const int fr = ln & 15, q8 = (ln >> 4) * 8;
  const int rowA = t >> 2, kc = (t & 3) * 8;

  f32x4 acc[4][4];
  #pragma unroll
  for (int i = 0; i < 4; i++)
    #pragma unroll
    for (int j = 0; j < 4; j++)
      #pragma unroll
      for (int r = 0; r < 4; r++) acc[i][j][r] = 0.f;

  for (int kk = 0; kk < 512; kk += 32) {
    #pragma unroll
    for (int s = 0; s < 2; s++) {
      async_ld16(A + (long)(s * 64 + rowA) * 512 + kk + kc, As + (s * 256 + wv * 64) * 8);
      async_ld16(B + (long)(n0 + s * 64 + rowA) * 512 + kk + kc, Bs + (s * 256 + wv * 64) * 8);
    }
    __syncthreads();
    short8 af[4], bfr[4];
    #pragma unroll
    for (int mi = 0; mi < 4; mi++) af[mi] = *(const short8*)&As[(wm + mi * 16 + fr) * 32 + q8];
    #pragma unroll
    for (int ni = 0; ni < 4; ni++) bfr[ni] = *(const short8*)&Bs[(wn + ni * 16 + fr) * 32 + q8];
    #pragma unroll
    for (int mi = 0; mi < 4; mi++)
      #pragma unroll
      for (int ni = 0; ni < 4; ni++)
        acc[mi][ni] = __builtin_amdgcn_mfma_f32_16x16x32_bf16(af[mi], bfr[ni], acc[mi][ni], 0, 0, 0);
    __syncthreads();
  }

  const int colb = n0 + wn + fr;
  const int rowb = m0 + wm + (ln >> 4) * 4;
  float cb[4];
  #pragma unroll
  for (int ni = 0; ni < 4; ni++) cb[ni] = bias[colb + ni * 16];
  #pragma unroll
  for (int mi = 0; mi < 4; mi++)
    #pragma unroll
    for (int r = 0; r < 4; r++) {
      const long mr = rowb + mi * 16 + r;
      #pragma unroll
      for (int ni = 0; ni < 4; ni++)
        TPT2[mr * 256 + colb + ni * 16] = f2bf(acc[mi][ni][r] + cb[ni]);
    }
}

// ---------------- scores: E = exp(TT2·PT2^T), fused column partial sums ----
// grid (16 m-blocks, 16 n-blocks, 8 b). Two K=256 segments (h=0,1).
__global__ __launch_bounds__(256)
void scores_k(const short* __restrict__ TT2, const short* __restrict__ PT2,
              short* __restrict__ ST, float* __restrict__ pstats)
{
  __shared__ __align__(16) short As[128 * 32];
  __shared__ __align__(16) short Bs[128 * 32];
  const int bz = blockIdx.z, by = blockIdx.y, bx = blockIdx.x;
  const int t = threadIdx.x;
  const int wv = t >> 6, ln = t & 63;
  const int wm = (wv >> 1) * 64, wn = (wv & 1) * 64;
  const int fr = ln & 15, q8 = (ln >> 4) * 8;
  const int rowA = t >> 2, kc = (t & 3) * 8;

  f32x4 acc[4][4];
  #pragma unroll
  for (int i = 0; i < 4; i++)
    #pragma unroll
    for (int j = 0; j < 4; j++)
      #pragma unroll
      for (int r = 0; r < 4; r++) acc[i][j][r] = 0.f;

  #pragma unroll
  for (int h = 0; h < 2; h++) {
    const short* Aseg = TT2 + ((long)(bz * 4096 + h * 2048 + by * 128)) * 256;
    const short* Bseg = PT2 + ((long)(bz * 4096 + h * 2048 + bx * 128)) * 256;
    for (int kk = 0; kk < 256; kk += 32) {
      #pragma unroll
      for (int s = 0; s < 2; s++) {
        async_ld16(Aseg + (long)(s * 64 + rowA) * 256 + kk + kc, As + (s * 256 + wv * 64) * 8);
        async_ld16(Bseg + (long)(s * 64 + rowA) * 256 + kk + kc, Bs + (s * 256 + wv * 64) * 8);
      }
      __syncthreads();
      short8 af[4], bfr[4];
      #pragma unroll
      for (int mi = 0; mi < 4; mi++) af[mi] = *(const short8*)&As[(wm + mi * 16 + fr) * 32 + q8];
      #pragma unroll
      for (int ni = 0; ni < 4; ni++) bfr[ni] = *(const short8*)&Bs[(wn + ni * 16 + fr) * 32 + q8];
      #pragma unroll
      for (int mi = 0; mi < 4; mi++)
        #pragma unroll
        for (int ni = 0; ni < 4; ni++)
          acc[mi][ni] = __builtin_amdgcn_mfma_f32_16x16x32_bf16(af[mi], bfr[ni], acc[mi][ni], 0, 0, 0);
      __syncthreads();
    }
  }

  // epilogue: E = exp(acc) (unnormalized, safe: |s| <~ 25), partial col sums
  const int colb = bx * 128 + wn + fr;
  const int rowb = by * 128 + wm + (ln >> 4) * 4;
  short* base = ST + ((long)bz << 22);
  float ps[4] = {0.f, 0.f, 0.f, 0.f};
  #pragma unroll
  for (int mi = 0; mi < 4; mi++)
    #pragma unroll
    for (int r = 0; r < 4; r++) {
      const long mr = rowb + mi * 16 + r;
      #pragma unroll
      for (int ni = 0; ni < 4; ni++) {
        float e = __expf(acc[mi][ni][r]);
        base[mr * 2048 + colb + ni * 16] = f2bf(e);
        ps[ni] += e;
      }
    }
  // quad merge: sum over the wave's 64 rows
  #pragma unroll
  for (int ni = 0; ni < 4; ni++) {
    ps[ni] += __shfl_xor(ps[ni], 16);
    ps[ni] += __shfl_xor(ps[ni], 32);
  }
  float* part = (float*)As;   // reuse LDS (loop ended with barrier)
  if (ln < 16) {
    #pragma unroll
    for (int ni = 0; ni < 4; ni++)
      part[(wv >> 1) * 128 + wn + ni * 16 + fr] = ps[ni];
  }
  __syncthreads();
  if (t < 128)
    pstats[((long)(bz * 16 + by)) * 2048 + bx * 128 + t] = part[t] + part[128 + t];
}

// ---------------- reduce 16 partials -> invZ per column --------------------
__global__ __launch_bounds__(256)
void zfinal(const float* __restrict__ pstats, float* __restrict__ invZ)
{
  const int g = blockIdx.x * 256 + threadIdx.x;   // 0..16383
  const int b = g >> 11, col = g & 2047;
  float S = 0.f;
  #pragma unroll
  for (int rc = 0; rc < 16; rc++) S += pstats[((long)(b * 16 + rc)) * 2048 + col];
  invZ[g] = 1.f / S;
}

// ---------------- G *= invZ[m] (in place), folds softmax denom -------------
__global__ __launch_bounds__(256)
void g_scale(short* __restrict__ G, const float* __restrict__ invZ)
{
  const long base = ((long)blockIdx.x * 256 + threadIdx.x) * 8;  // 8.4M elems
  const int bz = (int)(base >> 20);
  const int n2 = (int)(base & 4095);
  const float* z = invZ + bz * 2048 + (n2 & 2047);
  short8 v = *(short8*)&G[base];
  f32x4 z0 = *(const f32x4*)z;
  f32x4 z1 = *(const f32x4*)(z + 4);
  #pragma unroll
  for (int j = 0; j < 4; j++) { v[j] = f2bf(bf2f(v[j]) * z0[j]); v[4 + j] = f2bf(bf2f(v[4 + j]) * z1[j]); }
  *(short8*)&G[base] = v;
}

// ---------------- mask GEMM: zero-interleaved weights, bias+residual -------
__global__ __launch_bounds__(256)
void mask_k(const short* __restrict__ Wm20, const short* __restrict__ Wm21,
            const short* __restrict__ OVT, const float* __restrict__ bmask,
            const float* __restrict__ x, float* __restrict__ out)
{
  __shared__ __align__(16) short As[128 * 32];
  __shared__ __align__(16) short Bs[128 * 32];
  const int bz = blockIdx.z;
  const int n0 = blockIdx.x * 128;
  const int m0 = blockIdx.y * 128;
  const short* A = (n0 >= 2048) ? Wm21 : Wm20;
  const short* B = OVT + ((long)bz << 20) + (long)(n0 & 2047) * 512;
  const int t = threadIdx.x;
  const int wv = t >> 6, ln = t & 63;
  const int wm = (wv >> 1) * 64, wn = (wv & 1) * 64;
  const int fr = ln & 15, q8 = (ln >> 4) * 8;
  const int rowA = t >> 2, kc = (t & 3) * 8;

  f32x4 acc[4][4];
  #pragma unroll
  for (int i = 0; i < 4; i++)
    #pragma unroll
    for (int j = 0; j < 4; j++)
      #pragma unroll
      for (int r = 0; r < 4; r++) acc[i][j][r] = 0.f;

  for (int kk = 0; kk < 512; kk += 32) {
    #pragma unroll
    for (int s = 0; s < 2; s++) {
      async_ld16(A + (long)(m0 + s * 64 + rowA) * 512 + kk + kc, As + (s * 256 + wv * 64) * 8);
      async_ld16(B + (long)(s * 64 + rowA) * 512 + kk + kc, Bs + (s * 256 + wv * 64) * 8);
    }
    __syncthreads();
    short8 af[4], bfr[4];
    #pragma unroll
    for (int mi = 0; mi < 4; mi++) af[mi] = *(const short8*)&As[(wm + mi * 16 + fr) * 32 + q8];
    #pragma unroll
    for (int ni = 0; ni < 4; ni++) bfr[ni] = *(const short8*)&Bs[(wn + ni * 16 + fr) * 32 + q8];
    #pragma unroll
    for (int mi = 0; mi < 4; mi++)
      #pragma unroll
      for (int ni = 0; ni < 4; ni++)
        acc[mi][ni] = __builtin_amdgcn_mfma_f32_16x16x32_bf16(af[mi], bfr[ni], acc[mi][ni], 0, 0, 0);
    __syncthreads();
  }

  const int colb = n0 + wn + fr;
  const int rowb = m0 + wm + (ln >> 4) * 4;
  #pragma unroll
  for (int mi = 0; mi < 4; mi++)
    #pragma unroll
    for (int r = 0; r < 4; r++) {
      const int mr = rowb + mi * 16 + r;
      const float badd = bmask[mr];
      const long rbase = ((long)bz * 512 + mr) * 4096;
      #pragma unroll
      for (int ni = 0; ni < 4; ni++) {
        const int cc = colb + ni * 16;
        out[rbase + cc] = acc[mi][ni][r] + badd + x[rbase + cc];
      }
    }
}

// ---------------- weight prep ----------------------------------------------
__global__ __launch_bounds__(256)
void wconv2(const float* w_phi, const float* w_theta, const float* w_g,
            const float* w_mask,
            short* wph, short* wth, short* wg, short* Wm20, short* Wm21)
{
  const int seg = blockIdx.x >> 6;
  const int blk = blockIdx.x & 63;
  const int i0 = blk * 2048 + threadIdx.x * 8;
  if (seg < 3) {
    const float* s = seg == 0 ? w_phi : seg == 1 ? w_theta : w_g;
    short* d = seg == 0 ? wph : seg == 1 ? wth : wg;
    f32x4 a = *(const f32x4*)&s[i0];
    f32x4 b = *(const f32x4*)&s[i0 + 4];
    short8 o;
    #pragma unroll
    for (int j = 0; j < 4; j++) { o[j] = f2bf(a[j]); o[4 + j] = f2bf(b[j]); }
    *(short8*)&d[i0] = o;
  } else {
    const int o = i0 >> 8;
    f32x4 a = *(const f32x4*)&w_mask[i0];
    f32x4 b = *(const f32x4*)&w_mask[i0 + 4];
    short v[8];
    #pragma unroll
    for (int j = 0; j < 4; j++) { v[j] = f2bf(a[j]); v[4 + j] = f2bf(b[j]); }
    short8 a0, a1, b0, b1;
    #pragma unroll
    for (int j = 0; j < 4; j++) {
      a0[2 * j] = v[j];     a0[2 * j + 1] = 0;
      a1[2 * j] = v[4 + j]; a1[2 * j + 1] = 0;
      b0[2 * j] = 0;        b0[2 * j + 1] = v[j];
      b1[2 * j] = 0;        b1[2 * j + 1] = v[4 + j];
    }
    const long base = (long)o * 512 + 2 * (i0 & 255);
    *(short8*)&Wm20[base] = a0; *(short8*)&Wm20[base + 8] = a1;
    *(short8*)&Wm21[base] = b0; *(short8*)&Wm21[base + 8] = b1;
  }
}

// ---------------- convert + transpose images -------------------------------
__global__ __launch_bounds__(256)
void convtr(const float* __restrict__ x, const float* __restrict__ y,
            short* __restrict__ xT, short* __restrict__ yT)
{
  __shared__ short Ts[64 * 65];
  const int z = blockIdx.z;
  const float* src = (z < 8 ? x : y) + (long)(z & 7) * 512 * 4096;
  short* dst = (z < 8 ? xT : yT) + (long)(z & 7) * 4096 * 512;
  const int c0 = blockIdx.y * 64;
  const int n0 = blockIdx.x * 64;
  const int t = threadIdx.x;
  #pragma unroll
  for (int i = 0; i < 4; i++) {
    const int idx4 = t + i * 256;
    const int rr = idx4 >> 4, p4 = idx4 & 15;
    f32x4 v = *(const f32x4*)&src[(long)(c0 + rr) * 4096 + n0 + p4 * 4];
    #pragma unroll
    for (int j = 0; j < 4; j++) Ts[(p4 * 4 + j) * 65 + rr] = f2bf(v[j]);
  }
  __syncthreads();
  #pragma unroll
  for (int i = 0; i < 4; i++) {
    const int idx4 = t + i * 256;
    const int cc = idx4 >> 4, p4 = idx4 & 15;
    short4v o;
    #pragma unroll
    for (int j = 0; j < 4; j++) o[j] = Ts[cc * 65 + p4 * 4 + j];
    *(short4v*)&dst[(long)(n0 + cc) * 512 + c0 + p4 * 4] = o;
  }
}

// ---------------------------------------------------------------------------
extern "C" void kernel_launch(void* const* d_in, const int* in_sizes, int n_in,
                              void* d_out, int out_size, void* d_ws, size_t ws_size,
                              hipStream_t stream)
{
  (void)in_sizes; (void)n_in; (void)out_size; (void)ws_size;
  const float* x       = (const float*)d_in[0];
  const float* y       = (const float*)d_in[1];
  const float* w_phi   = (const float*)d_in[2];
  const float* b_phi   = (const float*)d_in[3];
  const float* w_theta = (const float*)d_in[4];
  const float* b_theta = (const float*)d_in[5];
  const float* w_g     = (const float*)d_in[6];
  const float* b_g     = (const float*)d_in[7];
  const float* w_mask  = (const float*)d_in[8];
  const float* b_mask  = (const float*)d_in[9];
  float* out = (float*)d_out;

  char* ws = (char*)d_ws;
  const long MB = 1L << 20;
  short* wph  = (short*)(ws + 0);
  short* wth  = (short*)(ws + 256 * 1024);
  short* wg   = (short*)(ws + 512 * 1024);
  short* Wm20 = (short*)(ws + 768 * 1024);
  short* Wm21 = (short*)(ws + 1280 * 1024);
  short* xT   = (short*)(ws + 2 * MB);    // [8][4096][512], 32MB
  short* yT   = (short*)(ws + 34 * MB);   // 32MB
  short* TPT2 = (short*)(ws + 66 * MB);   // [65536][256], 32MB
  short* G    = (short*)(ws + 98 * MB);   // [8][256][4096], 16MB
  short* ST   = (short*)(ws + 2 * MB);    // [8][2048][2048] E, 64MB (over xT/yT, dead)
  float* pstats = (float*)(ws + 114 * MB);  // [8][16][2048] f32, 1MB
  float* invZ   = (float*)(ws + 115 * MB);  // [8][2048] f32, 64KB
  short* OVT  = (short*)(ws + 66 * MB);   // [8][2048][512], 16MB (over TPT2, dead)

  dim3 blk(256, 1, 1);
  dim3 blk8(512, 1, 1);

  wconv2<<<dim3(256, 1, 1), blk, 0, stream>>>(w_phi, w_theta, w_g, w_mask,
                                              wph, wth, wg, Wm20, Wm21);
  convtr<<<dim3(64, 8, 16), blk, 0, stream>>>(x, y, xT, yT);

  // phi+theta pixel-major conv
  conv_pt<<<dim3(2, 512, 1), blk, 0, stream>>>(xT, wth, wph, b_theta, b_phi, TPT2);

  // g conv channel-major (8-wave): G[b][256][4096]
  gemm8<EPI_BF16_BIAS><<<dim3(32, 2, 8), blk8, 0, stream>>>(
      wg, 0, 512, xT, 4096L * 512, 512, G, 1048576L, 4096, 512, b_g);

  // scores -> E (unnormalized exp) + partial column sums
  scores_k<<<dim3(16, 16, 8), blk, 0, stream>>>(TPT2, TPT2 + 32768L * 256, ST, pstats);
  zfinal<<<dim3(64, 1, 1), blk, 0, stream>>>(pstats, invZ);

  // fold 1/Z into G columns
  g_scale<<<dim3(4096, 1, 1), blk, 0, stream>>>(G, invZ);

  // OVT[n][c] = sum_m E[n][m] * G''[c][m]  (8-wave)
  gemm8<EPI_BF16><<<dim3(4, 16, 8), blk8, 0, stream>>>(
      ST, 4194304L, 2048, G, 1048576L, 2048, OVT, 1048576L, 512, 2048, nullptr);

  // mask + bias + residual, fp32 out
  mask_k<<<dim3(32, 4, 8), blk, 0, stream>>>(Wm20, Wm21, OVT, b_mask, x, out);
}

// Round 5
// 393.271 us; speedup vs baseline: 1.2116x; 1.0293x over previous
//
#include <hip/hip_runtime.h>
#include <hip/hip_bf16.h>

// Non-local block, B=8 C=512 H=W=64, IC=256, N2=HW=4096, N=2048 (folded).
//
// Round-5: convtr v2 (deeper MLP, swizzled LDS, 256B store chunks) and
// XCD-locality-swizzled OV GEMM. Rest identical to round 4.

typedef __attribute__((ext_vector_type(8))) short short8;
typedef __attribute__((ext_vector_type(4))) short short4v;
typedef __attribute__((ext_vector_type(4))) float f32x4;

enum { EPI_BF16 = 0, EPI_BF16_BIAS = 1 };

__device__ __forceinline__ short f2bf(float f) {
  union { __hip_bfloat16 h; short s; } u; u.h = __float2bfloat16(f); return u.s;
}
__device__ __forceinline__ float bf2f(short s) {
  union { short s; __hip_bfloat16 h; } u; u.s = s; return __bfloat162float(u.h);
}

__device__ __forceinline__ void async_ld16(const void* g, void* l) {
  __builtin_amdgcn_global_load_lds(
      (const __attribute__((address_space(1))) unsigned int*)(unsigned long long)g,
      (__attribute__((address_space(3))) unsigned int*)(unsigned int)(unsigned long long)l,
      16, 0, 0);
}

// ---------------- 8-wave 128x128 GEMM: C[i][j] = sum_k A[i][k]*BT[j][k] ----
template<int EPI>
__global__ __launch_bounds__(512, 4)
void gemm8(const short* __restrict__ Ag, long sA, int lda,
           const short* __restrict__ Bg, long sB, int ldb,
           short* __restrict__ Cg, long sC, int ldc,
           int K, const float* __restrict__ bias)
{
  __shared__ __align__(16) short As[128 * 32];
  __shared__ __align__(16) short Bs[128 * 32];
  const int bz = blockIdx.z;
  const short* A = Ag + (long)bz * sA;
  const short* B = Bg + (long)bz * sB;
  const int m0 = blockIdx.y * 128;
  const int n0 = blockIdx.x * 128;
  const int t = threadIdx.x;
  const int wv = t >> 6, ln = t & 63;
  const int wr = wv >> 1, wc = wv & 1;
  const int fr = ln & 15, q8 = (ln >> 4) * 8;
  const int rowA = t >> 2, kc = (t & 3) * 8;

  f32x4 acc[2][4];
  #pragma unroll
  for (int i = 0; i < 2; i++)
    #pragma unroll
    for (int j = 0; j < 4; j++)
      #pragma unroll
      for (int r = 0; r < 4; r++) acc[i][j][r] = 0.f;

  for (int kk = 0; kk < K; kk += 32) {
    async_ld16(A + (long)(m0 + rowA) * lda + kk + kc, As + wv * 512);
    async_ld16(B + (long)(n0 + rowA) * ldb + kk + kc, Bs + wv * 512);
    __syncthreads();
    short8 af[2], bfr[4];
    #pragma unroll
    for (int mi = 0; mi < 2; mi++) af[mi] = *(const short8*)&As[(wr * 32 + mi * 16 + fr) * 32 + q8];
    #pragma unroll
    for (int ni = 0; ni < 4; ni++) bfr[ni] = *(const short8*)&Bs[(wc * 64 + ni * 16 + fr) * 32 + q8];
    #pragma unroll
    for (int mi = 0; mi < 2; mi++)
      #pragma unroll
      for (int ni = 0; ni < 4; ni++)
        acc[mi][ni] = __builtin_amdgcn_mfma_f32_16x16x32_bf16(af[mi], bfr[ni], acc[mi][ni], 0, 0, 0);
    __syncthreads();
  }

  const int colb = n0 + wc * 64 + fr;
  const int rowb = m0 + wr * 32 + (ln >> 4) * 4;
  #pragma unroll
  for (int mi = 0; mi < 2; mi++)
    #pragma unroll
    for (int r = 0; r < 4; r++) {
      const int mr = rowb + mi * 16 + r;
      float badd = 0.f;
      if constexpr (EPI == EPI_BF16_BIAS) badd = bias[mr];
      #pragma unroll
      for (int ni = 0; ni < 4; ni++)
        Cg[(long)bz * sC + (long)mr * ldc + colb + ni * 16] = f2bf(acc[mi][ni][r] + badd);
    }
}

// ---------------- OV GEMM with XCD-locality swizzle ------------------------
// OVT[b][n][c] = sum_m E[n][m]*G''[c][m]. 512 blocks; all 4 c-blocks of one
// (b,n) E-slab land on the same XCD (launch id === slab mod 8) so the 512KB
// slab is served from that XCD's L2 after the first pull.
__global__ __launch_bounds__(512, 4)
void ov_k(const short* __restrict__ Eg, const short* __restrict__ Gg,
          short* __restrict__ Cg)
{
  const int L = blockIdx.x;
  const int xcd = L & 7, k = L >> 3;
  const int slab = xcd + ((k >> 2) << 3);   // 0..127
  const int bz = slab >> 4, by = slab & 15, bx = k & 3;

  __shared__ __align__(16) short As[128 * 32];
  __shared__ __align__(16) short Bs[128 * 32];
  const short* A = Eg + ((long)bz << 22);
  const short* B = Gg + ((long)bz << 20);
  const int m0 = by * 128;
  const int n0 = bx * 128;
  const int t = threadIdx.x;
  const int wv = t >> 6, ln = t & 63;
  const int wr = wv >> 1, wc = wv & 1;
  const int fr = ln & 15, q8 = (ln >> 4) * 8;
  const int rowA = t >> 2, kc = (t & 3) * 8;

  f32x4 acc[2][4];
  #pragma unroll
  for (int i = 0; i < 2; i++)
    #pragma unroll
    for (int j = 0; j < 4; j++)
      #pragma unroll
      for (int r = 0; r < 4; r++) acc[i][j][r] = 0.f;

  for (int kk = 0; kk < 2048; kk += 32) {
    async_ld16(A + (long)(m0 + rowA) * 2048 + kk + kc, As + wv * 512);
    async_ld16(B + (long)(n0 + rowA) * 2048 + kk + kc, Bs + wv * 512);
    __syncthreads();
    short8 af[2], bfr[4];
    #pragma unroll
    for (int mi = 0; mi < 2; mi++) af[mi] = *(const short8*)&As[(wr * 32 + mi * 16 + fr) * 32 + q8];
    #pragma unroll
    for (int ni = 0; ni < 4; ni++) bfr[ni] = *(const short8*)&Bs[(wc * 64 + ni * 16 + fr) * 32 + q8];
    #pragma unroll
    for (int mi = 0; mi < 2; mi++)
      #pragma unroll
      for (int ni = 0; ni < 4; ni++)
        acc[mi][ni] = __builtin_amdgcn_mfma_f32_16x16x32_bf16(af[mi], bfr[ni], acc[mi][ni], 0, 0, 0);
    __syncthreads();
  }

  const int colb = n0 + wc * 64 + fr;
  const int rowb = m0 + wr * 32 + (ln >> 4) * 4;
  #pragma unroll
  for (int mi = 0; mi < 2; mi++)
    #pragma unroll
    for (int r = 0; r < 4; r++) {
      const int mr = rowb + mi * 16 + r;
      #pragma unroll
      for (int ni = 0; ni < 4; ni++)
        Cg[((long)bz << 20) + (long)mr * 512 + colb + ni * 16] = f2bf(acc[mi][ni][r]);
    }
}

// ---------------- pixel-major phi/theta conv: TPT2 = imgT · W^T + b --------
__global__ __launch_bounds__(256)
void conv_pt(const short* __restrict__ imgT,
             const short* __restrict__ wth, const short* __restrict__ wph,
             const float* __restrict__ bth, const float* __restrict__ bph,
             short* __restrict__ TPT2)
{
  __shared__ __align__(16) short As[128 * 32];
  __shared__ __align__(16) short Bs[128 * 32];
  const int m0 = blockIdx.y * 128;
  const int n0 = blockIdx.x * 128;
  const bool isphi = blockIdx.y >= 256;
  const short* A = imgT + (long)m0 * 512;
  const short* B = isphi ? wph : wth;
  const float* bias = isphi ? bph : bth;
  const int t = threadIdx.x;
  const int wv = t >> 6, ln = t & 63;
  const int wm = (wv >> 1) * 64, wn = (wv & 1) * 64;
  const int fr = ln & 15, q8 = (ln >> 4) * 8;
  const int rowA = t >> 2, kc = (t & 3) * 8;

  f32x4 acc[4][4];
  #pragma unroll
  for (int i = 0; i < 4; i++)
    #pragma unroll
    for (int j = 0; j < 4; j++)
      #pragma unroll
      for (int r = 0; r < 4; r++) acc[i][j][r] = 0.f;

  for (int kk = 0; kk < 512; kk += 32) {
    #pragma unroll
    for (int s = 0; s < 2; s++) {
      async_ld16(A + (long)(s * 64 + rowA) * 512 + kk + kc, As + (s * 256 + wv * 64) * 8);
      async_ld16(B + (long)(n0 + s * 64 + rowA) * 512 + kk + kc, Bs + (s * 256 + wv * 64) * 8);
    }
    __syncthreads();
    short8 af[4], bfr[4];
    #pragma unroll
    for (int mi = 0; mi < 4; mi++) af[mi] = *(const short8*)&As[(wm + mi * 16 + fr) * 32 + q8];
    #pragma unroll
    for (int ni = 0; ni < 4; ni++) bfr[ni] = *(const short8*)&Bs[(wn + ni * 16 + fr) * 32 + q8];
    #pragma unroll
    for (int mi = 0; mi < 4; mi++)
      #pragma unroll
      for (int ni = 0; ni < 4; ni++)
        acc[mi][ni] = __builtin_amdgcn_mfma_f32_16x16x32_bf16(af[mi], bfr[ni], acc[mi][ni], 0, 0, 0);
    __syncthreads();
  }

  const int colb = n0 + wn + fr;
  const int rowb = m0 + wm + (ln >> 4) * 4;
  float cb[4];
  #pragma unroll
  for (int ni = 0; ni < 4; ni++) cb[ni] = bias[colb + ni * 16];
  #pragma unroll
  for (int mi = 0; mi < 4; mi++)
    #pragma unroll
    for (int r = 0; r < 4; r++) {
      const long mr = rowb + mi * 16 + r;
      #pragma unroll
      for (int ni = 0; ni < 4; ni++)
        TPT2[mr * 256 + colb + ni * 16] = f2bf(acc[mi][ni][r] + cb[ni]);
    }
}

// ---------------- scores: E = exp(TT2·PT2^T), fused column partial sums ----
__global__ __launch_bounds__(256)
void scores_k(const short* __restrict__ TT2, const short* __restrict__ PT2,
              short* __restrict__ ST, float* __restrict__ pstats)
{
  __shared__ __align__(16) short As[128 * 32];
  __shared__ __align__(16) short Bs[128 * 32];
  const int bz = blockIdx.z, by = blockIdx.y, bx = blockIdx.x;
  const int t = threadIdx.x;
  const int wv = t >> 6, ln = t & 63;
  const int wm = (wv >> 1) * 64, wn = (wv & 1) * 64;
  const int fr = ln & 15, q8 = (ln >> 4) * 8;
  const int rowA = t >> 2, kc = (t & 3) * 8;

  f32x4 acc[4][4];
  #pragma unroll
  for (int i = 0; i < 4; i++)
    #pragma unroll
    for (int j = 0; j < 4; j++)
      #pragma unroll
      for (int r = 0; r < 4; r++) acc[i][j][r] = 0.f;

  #pragma unroll
  for (int h = 0; h < 2; h++) {
    const short* Aseg = TT2 + ((long)(bz * 4096 + h * 2048 + by * 128)) * 256;
    const short* Bseg = PT2 + ((long)(bz * 4096 + h * 2048 + bx * 128)) * 256;
    for (int kk = 0; kk < 256; kk += 32) {
      #pragma unroll
      for (int s = 0; s < 2; s++) {
        async_ld16(Aseg + (long)(s * 64 + rowA) * 256 + kk + kc, As + (s * 256 + wv * 64) * 8);
        async_ld16(Bseg + (long)(s * 64 + rowA) * 256 + kk + kc, Bs + (s * 256 + wv * 64) * 8);
      }
      __syncthreads();
      short8 af[4], bfr[4];
      #pragma unroll
      for (int mi = 0; mi < 4; mi++) af[mi] = *(const short8*)&As[(wm + mi * 16 + fr) * 32 + q8];
      #pragma unroll
      for (int ni = 0; ni < 4; ni++) bfr[ni] = *(const short8*)&Bs[(wn + ni * 16 + fr) * 32 + q8];
      #pragma unroll
      for (int mi = 0; mi < 4; mi++)
        #pragma unroll
        for (int ni = 0; ni < 4; ni++)
          acc[mi][ni] = __builtin_amdgcn_mfma_f32_16x16x32_bf16(af[mi], bfr[ni], acc[mi][ni], 0, 0, 0);
      __syncthreads();
    }
  }

  const int colb = bx * 128 + wn + fr;
  const int rowb = by * 128 + wm + (ln >> 4) * 4;
  short* base = ST + ((long)bz << 22);
  float ps[4] = {0.f, 0.f, 0.f, 0.f};
  #pragma unroll
  for (int mi = 0; mi < 4; mi++)
    #pragma unroll
    for (int r = 0; r < 4; r++) {
      const long mr = rowb + mi * 16 + r;
      #pragma unroll
      for (int ni = 0; ni < 4; ni++) {
        float e = __expf(acc[mi][ni][r]);
        base[mr * 2048 + colb + ni * 16] = f2bf(e);
        ps[ni] += e;
      }
    }
  #pragma unroll
  for (int ni = 0; ni < 4; ni++) {
    ps[ni] += __shfl_xor(ps[ni], 16);
    ps[ni] += __shfl_xor(ps[ni], 32);
  }
  float* part = (float*)As;
  if (ln < 16) {
    #pragma unroll
    for (int ni = 0; ni < 4; ni++)
      part[(wv >> 1) * 128 + wn + ni * 16 + fr] = ps[ni];
  }
  __syncthreads();
  if (t < 128)
    pstats[((long)(bz * 16 + by)) * 2048 + bx * 128 + t] = part[t] + part[128 + t];
}

// ---------------- reduce 16 partials -> invZ per column --------------------
__global__ __launch_bounds__(256)
void zfinal(const float* __restrict__ pstats, float* __restrict__ invZ)
{
  const int g = blockIdx.x * 256 + threadIdx.x;
  const int b = g >> 11, col = g & 2047;
  float S = 0.f;
  #pragma unroll
  for (int rc = 0; rc < 16; rc++) S += pstats[((long)(b * 16 + rc)) * 2048 + col];
  invZ[g] = 1.f / S;
}

// ---------------- G *= invZ[m] (in place) ----------------------------------
__global__ __launch_bounds__(256)
void g_scale(short* __restrict__ G, const float* __restrict__ invZ)
{
  const long base = ((long)blockIdx.x * 256 + threadIdx.x) * 8;
  const int bz = (int)(base >> 20);
  const int n2 = (int)(base & 4095);
  const float* z = invZ + bz * 2048 + (n2 & 2047);
  short8 v = *(short8*)&G[base];
  f32x4 z0 = *(const f32x4*)z;
  f32x4 z1 = *(const f32x4*)(z + 4);
  #pragma unroll
  for (int j = 0; j < 4; j++) { v[j] = f2bf(bf2f(v[j]) * z0[j]); v[4 + j] = f2bf(bf2f(v[4 + j]) * z1[j]); }
  *(short8*)&G[base] = v;
}

// ---------------- mask GEMM ------------------------------------------------
__global__ __launch_bounds__(256)
void mask_k(const short* __restrict__ Wm20, const short* __restrict__ Wm21,
            const short* __restrict__ OVT, const float* __restrict__ bmask,
            const float* __restrict__ x, float* __restrict__ out)
{
  __shared__ __align__(16) short As[128 * 32];
  __shared__ __align__(16) short Bs[128 * 32];
  const int bz = blockIdx.z;
  const int n0 = blockIdx.x * 128;
  const int m0 = blockIdx.y * 128;
  const short* A = (n0 >= 2048) ? Wm21 : Wm20;
  const short* B = OVT + ((long)bz << 20) + (long)(n0 & 2047) * 512;
  const int t = threadIdx.x;
  const int wv = t >> 6, ln = t & 63;
  const int wm = (wv >> 1) * 64, wn = (wv & 1) * 64;
  const int fr = ln & 15, q8 = (ln >> 4) * 8;
  const int rowA = t >> 2, kc = (t & 3) * 8;

  f32x4 acc[4][4];
  #pragma unroll
  for (int i = 0; i < 4; i++)
    #pragma unroll
    for (int j = 0; j < 4; j++)
      #pragma unroll
      for (int r = 0; r < 4; r++) acc[i][j][r] = 0.f;

  for (int kk = 0; kk < 512; kk += 32) {
    #pragma unroll
    for (int s = 0; s < 2; s++) {
      async_ld16(A + (long)(m0 + s * 64 + rowA) * 512 + kk + kc, As + (s * 256 + wv * 64) * 8);
      async_ld16(B + (long)(s * 64 + rowA) * 512 + kk + kc, Bs + (s * 256 + wv * 64) * 8);
    }
    __syncthreads();
    short8 af[4], bfr[4];
    #pragma unroll
    for (int mi = 0; mi < 4; mi++) af[mi] = *(const short8*)&As[(wm + mi * 16 + fr) * 32 + q8];
    #pragma unroll
    for (int ni = 0; ni < 4; ni++) bfr[ni] = *(const short8*)&Bs[(wn + ni * 16 + fr) * 32 + q8];
    #pragma unroll
    for (int mi = 0; mi < 4; mi++)
      #pragma unroll
      for (int ni = 0; ni < 4; ni++)
        acc[mi][ni] = __builtin_amdgcn_mfma_f32_16x16x32_bf16(af[mi], bfr[ni], acc[mi][ni], 0, 0, 0);
    __syncthreads();
  }

  const int colb = n0 + wn + fr;
  const int rowb = m0 + wm + (ln >> 4) * 4;
  #pragma unroll
  for (int mi = 0; mi < 4; mi++)
    #pragma unroll
    for (int r = 0; r < 4; r++) {
      const int mr = rowb + mi * 16 + r;
      const float badd = bmask[mr];
      const long rbase = ((long)bz * 512 + mr) * 4096;
      #pragma unroll
      for (int ni = 0; ni < 4; ni++) {
        const int cc = colb + ni * 16;
        out[rbase + cc] = acc[mi][ni][r] + badd + x[rbase + cc];
      }
    }
}

// ---------------- weight prep ----------------------------------------------
__global__ __launch_bounds__(256)
void wconv2(const float* w_phi, const float* w_theta, const float* w_g,
            const float* w_mask,
            short* wph, short* wth, short* wg, short* Wm20, short* Wm21)
{
  const int seg = blockIdx.x >> 6;
  const int blk = blockIdx.x & 63;
  const int i0 = blk * 2048 + threadIdx.x * 8;
  if (seg < 3) {
    const float* s = seg == 0 ? w_phi : seg == 1 ? w_theta : w_g;
    short* d = seg == 0 ? wph : seg == 1 ? wth : wg;
    f32x4 a = *(const f32x4*)&s[i0];
    f32x4 b = *(const f32x4*)&s[i0 + 4];
    short8 o;
    #pragma unroll
    for (int j = 0; j < 4; j++) { o[j] = f2bf(a[j]); o[4 + j] = f2bf(b[j]); }
    *(short8*)&d[i0] = o;
  } else {
    const int o = i0 >> 8;
    f32x4 a = *(const f32x4*)&w_mask[i0];
    f32x4 b = *(const f32x4*)&w_mask[i0 + 4];
    short v[8];
    #pragma unroll
    for (int j = 0; j < 4; j++) { v[j] = f2bf(a[j]); v[4 + j] = f2bf(b[j]); }
    short8 a0, a1, b0, b1;
    #pragma unroll
    for (int j = 0; j < 4; j++) {
      a0[2 * j] = v[j];     a0[2 * j + 1] = 0;
      a1[2 * j] = v[4 + j]; a1[2 * j + 1] = 0;
      b0[2 * j] = 0;        b0[2 * j + 1] = v[j];
      b1[2 * j] = 0;        b1[2 * j + 1] = v[4 + j];
    }
    const long base = (long)o * 512 + 2 * (i0 & 255);
    *(short8*)&Wm20[base] = a0; *(short8*)&Wm20[base + 8] = a1;
    *(short8*)&Wm21[base] = b0; *(short8*)&Wm21[base + 8] = b1;
  }
}

// ---------------- convert + transpose v2 -----------------------------------
// img[b][512][4096] f32 -> imgT[b][4096][512] bf16. Tile 64 px x 128 c.
// LDS Ts[px][c'] bf16, c' = c ^ (((px>>2)&3)<<3)  (swizzle: conflict-free
// b128 phase-2 reads, ~4-way phase-1 b16 writes). Stores: 256B/px-row.
__global__ __launch_bounds__(256)
void convtr(const float* __restrict__ x, const float* __restrict__ y,
            short* __restrict__ xT, short* __restrict__ yT)
{
  __shared__ __align__(16) short Ts[64 * 136];
  const int z = blockIdx.z;
  const float* src = (z < 8 ? x : y) + (long)(z & 7) * 512 * 4096;
  short* dst = (z < 8 ? xT : yT) + (long)(z & 7) * 4096 * 512;
  const int c0 = blockIdx.y * 128;
  const int n0 = blockIdx.x * 64;
  const int t = threadIdx.x;

  // phase 1: read 128 c-rows x 64 px fp32 (coalesced 256B per 16 lanes),
  // write bf16 transposed+swizzled into LDS.
  const int i16 = t & 15;          // px group (4 px each)
  const int rbase = t >> 4;        // c row 0..15, step 16
  const int sw = (i16 & 3) << 3;   // swizzle for px>>2 == i16
  f32x4 v[8];
  #pragma unroll
  for (int p = 0; p < 8; p++)
    v[p] = *(const f32x4*)&src[(long)(c0 + p * 16 + rbase) * 4096 + n0 + i16 * 4];
  #pragma unroll
  for (int p = 0; p < 8; p++) {
    const int c = p * 16 + rbase;
    const int cs = c ^ sw;
    #pragma unroll
    for (int j = 0; j < 4; j++)
      Ts[(i16 * 4 + j) * 136 + cs] = f2bf(v[p][j]);
  }
  __syncthreads();

  // phase 2: b128 LDS reads (conflict-free), 256B-contiguous global stores.
  #pragma unroll
  for (int q = 0; q < 4; q++) {
    const int idx = q * 256 + t;
    const int px = idx >> 4;          // 0..63
    const int p16 = idx & 15;         // c chunk of 8
    const int sw2 = ((px >> 2) & 3) << 3;
    short8 o = *(const short8*)&Ts[px * 136 + ((p16 * 8) ^ sw2)];
    *(short8*)&dst[(long)(n0 + px) * 512 + c0 + p16 * 8] = o;
  }
}

// ---------------------------------------------------------------------------
extern "C" void kernel_launch(void* const* d_in, const int* in_sizes, int n_in,
                              void* d_out, int out_size, void* d_ws, size_t ws_size,
                              hipStream_t stream)
{
  (void)in_sizes; (void)n_in; (void)out_size; (void)ws_size;
  const float* x       = (const float*)d_in[0];
  const float* y       = (const float*)d_in[1];
  const float* w_phi   = (const float*)d_in[2];
  const float* b_phi   = (const float*)d_in[3];
  const float* w_theta = (const float*)d_in[4];
  const float* b_theta = (const float*)d_in[5];
  const float* w_g     = (const float*)d_in[6];
  const float* b_g     = (const float*)d_in[7];
  const float* w_mask  = (const float*)d_in[8];
  const float* b_mask  = (const float*)d_in[9];
  float* out = (float*)d_out;

  char* ws = (char*)d_ws;
  const long MB = 1L << 20;
  short* wph  = (short*)(ws + 0);
  short* wth  = (short*)(ws + 256 * 1024);
  short* wg   = (short*)(ws + 512 * 1024);
  short* Wm20 = (short*)(ws + 768 * 1024);
  short* Wm21 = (short*)(ws + 1280 * 1024);
  short* xT   = (short*)(ws + 2 * MB);    // [8][4096][512], 32MB
  short* yT   = (short*)(ws + 34 * MB);   // 32MB
  short* TPT2 = (short*)(ws + 66 * MB);   // [65536][256], 32MB
  short* G    = (short*)(ws + 98 * MB);   // [8][256][4096], 16MB
  short* ST   = (short*)(ws + 2 * MB);    // [8][2048][2048] E, 64MB (over xT/yT)
  float* pstats = (float*)(ws + 114 * MB);
  float* invZ   = (float*)(ws + 115 * MB);
  short* OVT  = (short*)(ws + 66 * MB);   // [8][2048][512], 16MB (over TPT2)

  dim3 blk(256, 1, 1);
  dim3 blk8(512, 1, 1);

  wconv2<<<dim3(256, 1, 1), blk, 0, stream>>>(w_phi, w_theta, w_g, w_mask,
                                              wph, wth, wg, Wm20, Wm21);
  convtr<<<dim3(64, 4, 16), blk, 0, stream>>>(x, y, xT, yT);

  conv_pt<<<dim3(2, 512, 1), blk, 0, stream>>>(xT, wth, wph, b_theta, b_phi, TPT2);

  gemm8<EPI_BF16_BIAS><<<dim3(32, 2, 8), blk8, 0, stream>>>(
      wg, 0, 512, xT, 4096L * 512, 512, G, 1048576L, 4096, 512, b_g);

  scores_k<<<dim3(16, 16, 8), blk, 0, stream>>>(TPT2, TPT2 + 32768L * 256, ST, pstats);
  zfinal<<<dim3(64, 1, 1), blk, 0, stream>>>(pstats, invZ);
  g_scale<<<dim3(4096, 1, 1), blk, 0, stream>>>(G, invZ);

  ov_k<<<dim3(512, 1, 1), blk8, 0, stream>>>(ST, G, OVT);

  mask_k<<<dim3(32, 4, 8), blk, 0, stream>>>(Wm20, Wm21, OVT, b_mask, x, out);
}